// Round 7
// baseline (295.910 us; speedup 1.0000x reference)
//
#include <hip/hip_runtime.h>
#include <hip/hip_bf16.h>

// XConv: N=32 P=1024 K=16 DIMS=3 C_IN=64 C_MID=64 C_OUT=128 DM=2; NP=32768
// ws: 32768*256 floats (33.5 MB): holds X2 (untransposed), overwritten in-place by tmp.

#define ELU(x) ((x) > 0.0f ? (x) : (__expf(x) - 1.0f))

__device__ __forceinline__ void lds_fence() {
    asm volatile("s_waitcnt lgkmcnt(0)" ::: "memory");
}

typedef __attribute__((ext_vector_type(8))) short short8v;
typedef __attribute__((ext_vector_type(4))) float f32x4;
#define MFMA32(a, b, c) __builtin_amdgcn_mfma_f32_16x16x32_bf16(a, b, c, 0, 0, 0)

__device__ __forceinline__ short f2bf(float x) {
    __hip_bfloat16 h = __float2bfloat16(x);
    return *reinterpret_cast<short*>(&h);
}
__device__ __forceinline__ float bf2f(short x) {
    unsigned u = ((unsigned)(unsigned short)x) << 16;
    return __uint_as_float(u);
}

// ---------------- Kernel 1: X-transform via MFMA (unchanged) ----------------
#define XW_WC   0        // bf16 frag entries: idx=(part*16+u)*64+lane, 16B each (8192 words)
#define XW_WD1  8192     // wdep1: i*260 + j*16 + k  (4160 words)
#define XW_WD2  12352    // wdep2 same               (4160)
#define XW_BC   16512    // bconv 256
#define XW_BD1  16768    // 256
#define XW_BD2  17024    // 256
#define XW_SCR  17280    // + wave*4368 : per-point stride 273, scr[p*273 + j*17 + s]
#define XW_TOTAL (17280 + 4*4368)   // 34752 words = 139008 B

__global__ __launch_bounds__(256) void k_xform(
    const float* __restrict__ rep, const float* __restrict__ pts,
    const float* __restrict__ wconv, const float* __restrict__ bconv,
    const float* __restrict__ wdep1, const float* __restrict__ bdep1,
    const float* __restrict__ wdep2, const float* __restrict__ bdep2,
    float* __restrict__ x2)
{
    extern __shared__ __align__(16) float sm[];
    short* smh = (short*)sm;
    const int tid = threadIdx.x;

    for (int e = tid; e < 2048; e += 256) {
        const int part = e >> 10, u = (e >> 6) & 15, l = e & 63;
        const int g = l >> 4, s = l & 15;
        const int o = u * 16 + s;
        short8v v;
        if (part == 0) {
            #pragma unroll
            for (int t = 0; t < 8; ++t) v[t] = f2bf(wconv[o*48 + g*8 + t]);
        } else {
            #pragma unroll
            for (int t = 0; t < 4; ++t) v[t] = f2bf(wconv[o*48 + 32 + g*4 + t]);
            #pragma unroll
            for (int t = 4; t < 8; ++t) v[t] = 0;
        }
        *(short8v*)&smh[e * 8] = v;
    }
    for (int e = tid; e < 4096; e += 256) {
        const int i = e >> 8, j = (e >> 4) & 15, k = e & 15;
        sm[XW_WD1 + i*260 + j*16 + k] = wdep1[e];
        sm[XW_WD2 + i*260 + j*16 + k] = wdep2[e];
    }
    sm[XW_BC  + tid] = bconv[tid];
    sm[XW_BD1 + tid] = bdep1[tid];
    sm[XW_BD2 + tid] = bdep2[tid];
    __syncthreads();

    const int wave = tid >> 6, lane = tid & 63;
    const int g = lane >> 4, s = lane & 15;
    const int pt0 = (blockIdx.x * 4 + wave) * 16;

    const int p = pt0 + s;
    const float r0 = rep[p*3], r1 = rep[p*3+1], r2 = rep[p*3+2];
    short8v ah0, al0, ah1, al1;
    #pragma unroll
    for (int e = 0; e < 8; ++e) {
        const int r = g*8 + e;
        const int d = g >> 1, k = r & 15;
        const float v = pts[p*48 + k*3 + d] - (d == 0 ? r0 : r1);
        const short h = f2bf(v);
        ah0[e] = h; al0[e] = f2bf(v - bf2f(h));
    }
    #pragma unroll
    for (int e = 0; e < 4; ++e) {
        const int k = g*4 + e;
        const float v = pts[p*48 + k*3 + 2] - r2;
        const short h = f2bf(v);
        ah1[e] = h; al1[e] = f2bf(v - bf2f(h));
    }
    #pragma unroll
    for (int e = 4; e < 8; ++e) { ah1[e] = 0; al1[e] = 0; }

    f32x4 ex[16];
    #pragma unroll
    for (int u = 0; u < 16; ++u) {
        const float b = sm[XW_BC + u*16 + s];
        f32x4 acc; acc[0] = b; acc[1] = b; acc[2] = b; acc[3] = b;
        const short8v bh0 = *(const short8v*)&smh[(u*64 + lane) * 8];
        const short8v bh1 = *(const short8v*)&smh[((16 + u)*64 + lane) * 8];
        acc = MFMA32(ah0, bh0, acc);
        acc = MFMA32(ah1, bh1, acc);
        acc = MFMA32(al0, bh0, acc);
        acc = MFMA32(al1, bh1, acc);
        f32x4 r;
        r[0] = ELU(acc[0]); r[1] = ELU(acc[1]); r[2] = ELU(acc[2]); r[3] = ELU(acc[3]);
        ex[u] = r;
    }

    const int scrb = XW_SCR + wave * 4368;
    #pragma unroll
    for (int j = 0; j < 16; ++j) {
        const float b = sm[XW_BD1 + s*16 + j];
        f32x4 a; a[0] = b; a[1] = b; a[2] = b; a[3] = b;
        #pragma unroll
        for (int kb = 0; kb < 4; ++kb) {
            const float4 w = *(const float4*)&sm[XW_WD1 + s*260 + j*16 + kb*4];
            a += ex[kb*4+0] * w.x; a += ex[kb*4+1] * w.y;
            a += ex[kb*4+2] * w.z; a += ex[kb*4+3] * w.w;
        }
        #pragma unroll
        for (int q = 0; q < 4; ++q)
            sm[scrb + (g*4+q)*273 + j*17 + s] = ELU(a[q]);
    }
    lds_fence();

    f32x4 xr[16];
    #pragma unroll
    for (int k = 0; k < 16; ++k) {
        f32x4 v;
        #pragma unroll
        for (int q = 0; q < 4; ++q)
            v[q] = sm[scrb + (g*4+q)*273 + s*17 + k];
        xr[k] = v;
    }
    f32x4 oj[16];
    #pragma unroll
    for (int j = 0; j < 16; ++j) {
        const float b = sm[XW_BD2 + s*16 + j];
        f32x4 a; a[0] = b; a[1] = b; a[2] = b; a[3] = b;
        #pragma unroll
        for (int kb = 0; kb < 4; ++kb) {
            const float4 w = *(const float4*)&sm[XW_WD2 + s*260 + j*16 + kb*4];
            a += xr[kb*4+0] * w.x; a += xr[kb*4+1] * w.y;
            a += xr[kb*4+2] * w.z; a += xr[kb*4+3] * w.w;
        }
        oj[j] = a;
    }
    #pragma unroll
    for (int q = 0; q < 4; ++q) {
        const int pp = pt0 + g*4 + q;
        #pragma unroll
        for (int jb = 0; jb < 4; ++jb) {
            *(float4*)&x2[pp*256 + s*16 + jb*4] =
                make_float4(oj[jb*4+0][q], oj[jb*4+1][q], oj[jb*4+2][q], oj[jb*4+3][q]);
        }
    }
}

// ---------------- Kernel 2: MFMA features; ALL weights in LDS (no persistent reg arrays) ----
// 8 points/wave; coalesced scalar fts loads + 1-pt-ahead prefetch. Per point: w2 B-frags via
// 8 ds_read_b128 (conflict-free: 64 lanes x consecutive 16B), w1/b1 via broadcast ds_read_b64.
// Persistent regs ~100 -> fits (256,4) cap 128 with slack: no spills, 16 waves/CU.
__global__ __launch_bounds__(256, 4) void k_feat(
    const float* __restrict__ rep, const float* __restrict__ pts, const float* __restrict__ fts,
    const float* __restrict__ w1, const float* __restrict__ b1,
    const float* __restrict__ w2, const float* __restrict__ b2,
    const float* __restrict__ wdw, const float* __restrict__ bdw,
    float* __restrict__ xbuf)
{
    __shared__ __align__(16) short sw2[4096];      // B-frags: rec r=nt*2+h, 16B @ (r*64+lane)
    __shared__ __align__(16) uint2 sw1[64];        // j: {pack(w1[0][j],w1[1][j]), pack(w1[2][j],b1[j])}
    __shared__ __align__(16) unsigned swdwp[2560]; // [m][c] stride 10 (all-32-bank b64 reads)
    __shared__ float sbdw[256];
    const int tid = threadIdx.x;

    for (int idx = tid; idx < 512; idx += 256) {   // 512 recs of 8 bf16
        const int r = idx >> 6, l = idx & 63;
        const int nt = r >> 1, h = r & 1, gg = l >> 4, ss = l & 15;
        short8v v;
        #pragma unroll
        for (int e = 0; e < 8; ++e)
            v[e] = f2bf(w2[(h*32 + gg*8 + e)*64 + nt*16 + ss]);
        *(short8v*)&sw2[idx * 8] = v;
    }
    if (tid < 64) {
        const int j = tid;
        uint2 v;
        v.x = (unsigned)(unsigned short)f2bf(w1[j])
            | (((unsigned)(unsigned short)f2bf(w1[64 + j])) << 16);
        v.y = (unsigned)(unsigned short)f2bf(w1[128 + j])
            | (((unsigned)(unsigned short)f2bf(b1[j])) << 16);
        sw1[j] = v;
    }
    for (int e = tid; e < 2048; e += 256) {
        const int m = e >> 10, c = (e >> 3) & 127, w = e & 7;
        const unsigned lo = (unsigned)(unsigned short)f2bf(wdw[c*32 + m*16 + 2*w]);
        const unsigned hi = (unsigned)(unsigned short)f2bf(wdw[c*32 + m*16 + 2*w + 1]);
        swdwp[m*1280 + c*10 + w] = lo | (hi << 16);
    }
    sbdw[tid] = bdw[tid];
    __syncthreads();

    const int lane = tid & 63, wave = tid >> 6;
    const int g = lane >> 4, s = lane & 15;

    float b2c[4];
    #pragma unroll
    for (int nt = 0; nt < 4; ++nt) b2c[nt] = b2[nt*16 + s];

    const int pt0 = (blockIdx.x * 4 + wave) * 8;

    // ---- prefetch point pt0 (coalesced: lanes sharing (g,e,ct) span s=0..15 -> 64B segs) ----
    float pf_f[16]; float4 pf_x; float pf_p0, pf_p1, pf_p2;
    {
        const int pt = pt0;
        #pragma unroll
        for (int ct = 0; ct < 4; ++ct)
            #pragma unroll
            for (int e = 0; e < 4; ++e)
                pf_f[ct*4+e] = fts[(size_t)pt*1024 + (g*4 + e)*64 + ct*16 + s];
        pf_x = *(const float4*)&xbuf[(size_t)pt*256 + s*16 + g*4];
        pf_p0 = pts[pt*48 + s*3 + 0] - rep[pt*3 + 0];
        pf_p1 = pts[pt*48 + s*3 + 1] - rep[pt*3 + 1];
        pf_p2 = pts[pt*48 + s*3 + 2] - rep[pt*3 + 2];
    }

    for (int it = 0; it < 8; ++it) {
        const int pt = pt0 + it;
        float cur_f[16];
        #pragma unroll
        for (int i = 0; i < 16; ++i) cur_f[i] = pf_f[i];
        const float4 xv = pf_x;
        const float p0 = pf_p0, p1 = pf_p1, p2 = pf_p2;
        if (it < 7) {
            const int np = pt + 1;
            #pragma unroll
            for (int ct = 0; ct < 4; ++ct)
                #pragma unroll
                for (int e = 0; e < 4; ++e)
                    pf_f[ct*4+e] = fts[(size_t)np*1024 + (g*4 + e)*64 + ct*16 + s];
            pf_x = *(const float4*)&xbuf[(size_t)np*256 + s*16 + g*4];
            pf_p0 = pts[np*48 + s*3 + 0] - rep[np*3 + 0];
            pf_p1 = pts[np*48 + s*3 + 1] - rep[np*3 + 1];
            pf_p2 = pts[np*48 + s*3 + 2] - rep[np*3 + 2];
        }

        // ---- phase A: h1 (w1/b1 broadcast from LDS) in A-frag layout; h2 via 8 MFMA ----
        short8v af0, af1;
        #pragma unroll
        for (int t = 0; t < 2; ++t) {
            short8v f;
            #pragma unroll
            for (int e = 0; e < 8; ++e) {
                const uint2 pk = sw1[t*32 + g*8 + e];
                const float wx = __uint_as_float(pk.x << 16);
                const float wy = __uint_as_float(pk.x & 0xffff0000u);
                const float wz = __uint_as_float(pk.y << 16);
                const float bb = __uint_as_float(pk.y & 0xffff0000u);
                float h = bb + p0*wx + p1*wy + p2*wz;
                h = ELU(h);
                f[e] = f2bf(h);
            }
            if (t == 0) af0 = f; else af1 = f;
        }
        f32x4 hacc[4];
        #pragma unroll
        for (int nt = 0; nt < 4; ++nt) {
            f32x4 a; a[0] = b2c[nt]; a[1] = b2c[nt]; a[2] = b2c[nt]; a[3] = b2c[nt];
            const short8v bf0 = *(const short8v*)&sw2[((nt*2 + 0)*64 + lane) * 8];
            const short8v bf1 = *(const short8v*)&sw2[((nt*2 + 1)*64 + lane) * 8];
            a = MFMA32(af0, bf0, a);
            a = MFMA32(af1, bf1, a);
            hacc[nt] = a;
        }
        short8v a2 = (short8v)0;
        a2[0] = f2bf(xv.x); a2[1] = f2bf(xv.y);
        a2[2] = f2bf(xv.z); a2[3] = f2bf(xv.w);

        // ---- phase B+C fused per 16-col tile u ----
        #pragma unroll
        for (int u = 0; u < 8; ++u) {
            short8v bfrag = (short8v)0;
            if (u < 4) {
                #pragma unroll
                for (int q = 0; q < 4; ++q) bfrag[q] = f2bf(ELU(hacc[u][q]));
            } else {
                #pragma unroll
                for (int e = 0; e < 4; ++e) bfrag[e] = f2bf(cur_f[(u-4)*4 + e]);
            }
            f32x4 z; z[0] = 0.f; z[1] = 0.f; z[2] = 0.f; z[3] = 0.f;
            const f32x4 fx = MFMA32(a2, bfrag, z);   // fts_X[4g+q][u*16+s]

            const int c = u*16 + s;
            const int wo = c*10 + 2*g;               // stride-10: banks (10s+2g)%32, all 32 used
            const uint2 wm0 = *(const uint2*)&swdwp[wo];
            const uint2 wm1 = *(const uint2*)&swdwp[1280 + wo];
            const float a0 = __uint_as_float(wm0.x << 16);
            const float a1 = __uint_as_float(wm0.x & 0xffff0000u);
            const float a2f = __uint_as_float(wm0.y << 16);
            const float a3 = __uint_as_float(wm0.y & 0xffff0000u);
            const float c0 = __uint_as_float(wm1.x << 16);
            const float c1 = __uint_as_float(wm1.x & 0xffff0000u);
            const float c2 = __uint_as_float(wm1.y << 16);
            const float c3 = __uint_as_float(wm1.y & 0xffff0000u);
            float q0 = fx[0]*a0 + fx[1]*a1 + fx[2]*a2f + fx[3]*a3;
            float q1 = fx[0]*c0 + fx[1]*c1 + fx[2]*c2 + fx[3]*c3;
            q0 += __shfl_xor(q0, 16); q0 += __shfl_xor(q0, 32);
            q1 += __shfl_xor(q1, 16); q1 += __shfl_xor(q1, 32);
            if (lane < 16) {
                float2 r; r.x = q0 + sbdw[2*c]; r.y = q1 + sbdw[2*c + 1];
                *(float2*)&xbuf[(size_t)pt*256 + 2*c] = r;
            }
        }
    }
}

// ---------------- Kernel 3: out = elu(tmp @ wpw^T + bpw) via MFMA (unchanged) ----------------
__global__ __launch_bounds__(256) void k_out(
    const float* __restrict__ tmp, const float* __restrict__ wpw,
    const float* __restrict__ bpw, float* __restrict__ out)
{
    __shared__ unsigned sb[16384];   // 64KB: [n][chunk cb^(n&7)][wi]
    const int tid = threadIdx.x;
    for (int e = tid; e < 16384; e += 256) {
        const int n = e >> 7, kw = e & 127;
        const int cb = kw >> 2, wi = kw & 3;
        const unsigned lo = (unsigned)(unsigned short)f2bf(wpw[n*256 + 2*kw]);
        const unsigned hi = (unsigned)(unsigned short)f2bf(wpw[n*256 + 2*kw + 1]);
        sb[n*128 + ((cb ^ (n & 7)) << 2) + wi] = lo | (hi << 16);
    }
    __syncthreads();

    const int lane = tid & 63, wave = tid >> 6;
    const int g = lane >> 4, s = lane & 15;
    const int row = blockIdx.x * 64 + wave * 16 + s;

    f32x4 acc[8];
    #pragma unroll
    for (int nt = 0; nt < 8; ++nt) {
        const float b = bpw[nt*16 + s];
        acc[nt][0] = b; acc[nt][1] = b; acc[nt][2] = b; acc[nt][3] = b;
    }

    const float* arow = tmp + (size_t)row * 256 + g*8;
    float4 pa0 = *(const float4*)(arow);
    float4 pa1 = *(const float4*)(arow + 4);

    #pragma unroll
    for (int kk = 0; kk < 8; ++kk) {
        const float4 a0 = pa0, a1 = pa1;
        if (kk < 7) {
            pa0 = *(const float4*)(arow + (kk+1)*32);
            pa1 = *(const float4*)(arow + (kk+1)*32 + 4);
        }
        short8v ah, al;
        const float av[8] = {a0.x, a0.y, a0.z, a0.w, a1.x, a1.y, a1.z, a1.w};
        #pragma unroll
        for (int e = 0; e < 8; ++e) {
            const short h = f2bf(av[e]);
            ah[e] = h;
            al[e] = f2bf(av[e] - bf2f(h));
        }
        #pragma unroll
        for (int nt = 0; nt < 8; ++nt) {
            const short8v bf = *(const short8v*)&sb[(nt*16 + s)*128 + (((kk*4 + g) ^ (s & 7)) << 2)];
            acc[nt] = MFMA32(ah, bf, acc[nt]);
            acc[nt] = MFMA32(al, bf, acc[nt]);
        }
    }
    const int rbase = blockIdx.x * 64 + wave * 16 + 4*g;
    #pragma unroll
    for (int nt = 0; nt < 8; ++nt)
        #pragma unroll
        for (int q = 0; q < 4; ++q)
            out[(size_t)(rbase + q) * 128 + nt*16 + s] = ELU(acc[nt][q]);
}

extern "C" void kernel_launch(void* const* d_in, const int* in_sizes, int n_in,
                              void* d_out, int out_size, void* d_ws, size_t ws_size,
                              hipStream_t stream)
{
    (void)in_sizes; (void)n_in; (void)out_size; (void)ws_size;
    const float* rep   = (const float*)d_in[0];
    const float* pts   = (const float*)d_in[1];
    const float* fts   = (const float*)d_in[2];
    const float* w1    = (const float*)d_in[3];
    const float* b1    = (const float*)d_in[4];
    const float* w2    = (const float*)d_in[5];
    const float* b2    = (const float*)d_in[6];
    const float* wconv = (const float*)d_in[7];
    const float* bconv = (const float*)d_in[8];
    const float* wdep1 = (const float*)d_in[9];
    const float* bdep1 = (const float*)d_in[10];
    const float* wdep2 = (const float*)d_in[11];
    const float* bdep2 = (const float*)d_in[12];
    const float* wdw   = (const float*)d_in[13];
    const float* bdw   = (const float*)d_in[14];
    const float* wpw   = (const float*)d_in[15];
    const float* bpw   = (const float*)d_in[16];
    float* out  = (float*)d_out;
    float* xbuf = (float*)d_ws;   // 32768*256 floats = 33.5 MB

    hipFuncSetAttribute((const void*)k_xform, hipFuncAttributeMaxDynamicSharedMemorySize, XW_TOTAL*4);

    k_xform<<<dim3(512),  dim3(256), XW_TOTAL*4, stream>>>(rep, pts, wconv, bconv, wdep1, bdep1, wdep2, bdep2, xbuf);
    k_feat <<<dim3(1024), dim3(256), 0, stream>>>(rep, pts, fts, w1, b1, w2, b2, wdw, bdw, xbuf);
    k_out  <<<dim3(512),  dim3(256), 0, stream>>>(xbuf, wpw, bpw, out);
}

// Round 8
// 245.274 us; speedup vs baseline: 1.2064x; 1.2064x over previous
//
#include <hip/hip_runtime.h>
#include <hip/hip_bf16.h>

// XConv: N=32 P=1024 K=16 DIMS=3 C_IN=64 C_MID=64 C_OUT=128 DM=2; NP=32768
// ws: 32768*256 floats (33.5 MB): holds X2 (untransposed), overwritten in-place by tmp.

#define ELU(x) ((x) > 0.0f ? (x) : (__expf(x) - 1.0f))

__device__ __forceinline__ void lds_fence() {
    asm volatile("s_waitcnt lgkmcnt(0)" ::: "memory");
}

typedef __attribute__((ext_vector_type(8))) short short8v;
typedef __attribute__((ext_vector_type(4))) float f32x4;
#define MFMA32(a, b, c) __builtin_amdgcn_mfma_f32_16x16x32_bf16(a, b, c, 0, 0, 0)

__device__ __forceinline__ short f2bf(float x) {
    __hip_bfloat16 h = __float2bfloat16(x);
    return *reinterpret_cast<short*>(&h);
}
__device__ __forceinline__ float bf2f(short x) {
    unsigned u = ((unsigned)(unsigned short)x) << 16;
    return __uint_as_float(u);
}

// ---------------- Kernel 1: X-transform via MFMA (unchanged) ----------------
#define XW_WC   0        // bf16 frag entries: idx=(part*16+u)*64+lane, 16B each (8192 words)
#define XW_WD1  8192     // wdep1: i*260 + j*16 + k  (4160 words)
#define XW_WD2  12352    // wdep2 same               (4160)
#define XW_BC   16512    // bconv 256
#define XW_BD1  16768    // 256
#define XW_BD2  17024    // 256
#define XW_SCR  17280    // + wave*4368 : per-point stride 273, scr[p*273 + j*17 + s]
#define XW_TOTAL (17280 + 4*4368)   // 34752 words = 139008 B

__global__ __launch_bounds__(256) void k_xform(
    const float* __restrict__ rep, const float* __restrict__ pts,
    const float* __restrict__ wconv, const float* __restrict__ bconv,
    const float* __restrict__ wdep1, const float* __restrict__ bdep1,
    const float* __restrict__ wdep2, const float* __restrict__ bdep2,
    float* __restrict__ x2)
{
    extern __shared__ __align__(16) float sm[];
    short* smh = (short*)sm;
    const int tid = threadIdx.x;

    for (int e = tid; e < 2048; e += 256) {
        const int part = e >> 10, u = (e >> 6) & 15, l = e & 63;
        const int g = l >> 4, s = l & 15;
        const int o = u * 16 + s;
        short8v v;
        if (part == 0) {
            #pragma unroll
            for (int t = 0; t < 8; ++t) v[t] = f2bf(wconv[o*48 + g*8 + t]);
        } else {
            #pragma unroll
            for (int t = 0; t < 4; ++t) v[t] = f2bf(wconv[o*48 + 32 + g*4 + t]);
            #pragma unroll
            for (int t = 4; t < 8; ++t) v[t] = 0;
        }
        *(short8v*)&smh[e * 8] = v;
    }
    for (int e = tid; e < 4096; e += 256) {
        const int i = e >> 8, j = (e >> 4) & 15, k = e & 15;
        sm[XW_WD1 + i*260 + j*16 + k] = wdep1[e];
        sm[XW_WD2 + i*260 + j*16 + k] = wdep2[e];
    }
    sm[XW_BC  + tid] = bconv[tid];
    sm[XW_BD1 + tid] = bdep1[tid];
    sm[XW_BD2 + tid] = bdep2[tid];
    __syncthreads();

    const int wave = tid >> 6, lane = tid & 63;
    const int g = lane >> 4, s = lane & 15;
    const int pt0 = (blockIdx.x * 4 + wave) * 16;

    const int p = pt0 + s;
    const float r0 = rep[p*3], r1 = rep[p*3+1], r2 = rep[p*3+2];
    short8v ah0, al0, ah1, al1;
    #pragma unroll
    for (int e = 0; e < 8; ++e) {
        const int r = g*8 + e;
        const int d = g >> 1, k = r & 15;
        const float v = pts[p*48 + k*3 + d] - (d == 0 ? r0 : r1);
        const short h = f2bf(v);
        ah0[e] = h; al0[e] = f2bf(v - bf2f(h));
    }
    #pragma unroll
    for (int e = 0; e < 4; ++e) {
        const int k = g*4 + e;
        const float v = pts[p*48 + k*3 + 2] - r2;
        const short h = f2bf(v);
        ah1[e] = h; al1[e] = f2bf(v - bf2f(h));
    }
    #pragma unroll
    for (int e = 4; e < 8; ++e) { ah1[e] = 0; al1[e] = 0; }

    f32x4 ex[16];
    #pragma unroll
    for (int u = 0; u < 16; ++u) {
        const float b = sm[XW_BC + u*16 + s];
        f32x4 acc; acc[0] = b; acc[1] = b; acc[2] = b; acc[3] = b;
        const short8v bh0 = *(const short8v*)&smh[(u*64 + lane) * 8];
        const short8v bh1 = *(const short8v*)&smh[((16 + u)*64 + lane) * 8];
        acc = MFMA32(ah0, bh0, acc);
        acc = MFMA32(ah1, bh1, acc);
        acc = MFMA32(al0, bh0, acc);
        acc = MFMA32(al1, bh1, acc);
        f32x4 r;
        r[0] = ELU(acc[0]); r[1] = ELU(acc[1]); r[2] = ELU(acc[2]); r[3] = ELU(acc[3]);
        ex[u] = r;
    }

    const int scrb = XW_SCR + wave * 4368;
    #pragma unroll
    for (int j = 0; j < 16; ++j) {
        const float b = sm[XW_BD1 + s*16 + j];
        f32x4 a; a[0] = b; a[1] = b; a[2] = b; a[3] = b;
        #pragma unroll
        for (int kb = 0; kb < 4; ++kb) {
            const float4 w = *(const float4*)&sm[XW_WD1 + s*260 + j*16 + kb*4];
            a += ex[kb*4+0] * w.x; a += ex[kb*4+1] * w.y;
            a += ex[kb*4+2] * w.z; a += ex[kb*4+3] * w.w;
        }
        #pragma unroll
        for (int q = 0; q < 4; ++q)
            sm[scrb + (g*4+q)*273 + j*17 + s] = ELU(a[q]);
    }
    lds_fence();

    f32x4 xr[16];
    #pragma unroll
    for (int k = 0; k < 16; ++k) {
        f32x4 v;
        #pragma unroll
        for (int q = 0; q < 4; ++q)
            v[q] = sm[scrb + (g*4+q)*273 + s*17 + k];
        xr[k] = v;
    }
    f32x4 oj[16];
    #pragma unroll
    for (int j = 0; j < 16; ++j) {
        const float b = sm[XW_BD2 + s*16 + j];
        f32x4 a; a[0] = b; a[1] = b; a[2] = b; a[3] = b;
        #pragma unroll
        for (int kb = 0; kb < 4; ++kb) {
            const float4 w = *(const float4*)&sm[XW_WD2 + s*260 + j*16 + kb*4];
            a += xr[kb*4+0] * w.x; a += xr[kb*4+1] * w.y;
            a += xr[kb*4+2] * w.z; a += xr[kb*4+3] * w.w;
        }
        oj[j] = a;
    }
    #pragma unroll
    for (int q = 0; q < 4; ++q) {
        const int pp = pt0 + g*4 + q;
        #pragma unroll
        for (int jb = 0; jb < 4; ++jb) {
            *(float4*)&x2[pp*256 + s*16 + jb*4] =
                make_float4(oj[jb*4+0][q], oj[jb*4+1][q], oj[jb*4+2][q], oj[jb*4+3][q]);
        }
    }
}

// ---------------- Kernel 2: MFMA features; LDS weights; NO prefetch (reg-min) ----------------
// 8 points/wave; per-iteration: 17 coalesced scalar loads at top, phase A (no fts dep) hides
// their latency, then fused B+C. Peak live regs ~80 incl. acc -> (256,4) cap 128 fits, no spill.
__global__ __launch_bounds__(256, 4) void k_feat(
    const float* __restrict__ rep, const float* __restrict__ pts, const float* __restrict__ fts,
    const float* __restrict__ w1, const float* __restrict__ b1,
    const float* __restrict__ w2, const float* __restrict__ b2,
    const float* __restrict__ wdw, const float* __restrict__ bdw,
    float* __restrict__ xbuf)
{
    __shared__ __align__(16) short sw2[4096];      // B-frags: rec r=nt*2+h, 16B @ (r*64+lane)
    __shared__ __align__(16) uint2 sw1[64];        // j: {pack(w1[0][j],w1[1][j]), pack(w1[2][j],b1[j])}
    __shared__ __align__(16) unsigned swdwp[2560]; // [m][c] stride 10 (all-32-bank b64 reads)
    __shared__ float sbdw[256];
    const int tid = threadIdx.x;

    for (int idx = tid; idx < 512; idx += 256) {   // 512 recs of 8 bf16
        const int r = idx >> 6, l = idx & 63;
        const int nt = r >> 1, h = r & 1, gg = l >> 4, ss = l & 15;
        short8v v;
        #pragma unroll
        for (int e = 0; e < 8; ++e)
            v[e] = f2bf(w2[(h*32 + gg*8 + e)*64 + nt*16 + ss]);
        *(short8v*)&sw2[idx * 8] = v;
    }
    if (tid < 64) {
        const int j = tid;
        uint2 v;
        v.x = (unsigned)(unsigned short)f2bf(w1[j])
            | (((unsigned)(unsigned short)f2bf(w1[64 + j])) << 16);
        v.y = (unsigned)(unsigned short)f2bf(w1[128 + j])
            | (((unsigned)(unsigned short)f2bf(b1[j])) << 16);
        sw1[j] = v;
    }
    for (int e = tid; e < 2048; e += 256) {
        const int m = e >> 10, c = (e >> 3) & 127, w = e & 7;
        const unsigned lo = (unsigned)(unsigned short)f2bf(wdw[c*32 + m*16 + 2*w]);
        const unsigned hi = (unsigned)(unsigned short)f2bf(wdw[c*32 + m*16 + 2*w + 1]);
        swdwp[m*1280 + c*10 + w] = lo | (hi << 16);
    }
    sbdw[tid] = bdw[tid];
    __syncthreads();

    const int lane = tid & 63, wave = tid >> 6;
    const int g = lane >> 4, s = lane & 15;

    float b2c[4];
    #pragma unroll
    for (int nt = 0; nt < 4; ++nt) b2c[nt] = b2[nt*16 + s];

    const int pt0 = (blockIdx.x * 4 + wave) * 8;

    for (int it = 0; it < 8; ++it) {
        const int pt = pt0 + it;

        // ---- issue all global loads for this point (coalesced 64B segments over s) ----
        float fr[16];
        #pragma unroll
        for (int ct = 0; ct < 4; ++ct)
            #pragma unroll
            for (int e = 0; e < 4; ++e)
                fr[ct*4+e] = fts[(size_t)pt*1024 + (g*4 + e)*64 + ct*16 + s];
        const float4 xv = *(const float4*)&xbuf[(size_t)pt*256 + s*16 + g*4];
        const float p0 = pts[pt*48 + s*3 + 0] - rep[pt*3 + 0];
        const float p1 = pts[pt*48 + s*3 + 1] - rep[pt*3 + 1];
        const float p2 = pts[pt*48 + s*3 + 2] - rep[pt*3 + 2];

        // ---- phase A: h1 (w1/b1 broadcast from LDS) in A-frag layout; h2 via 8 MFMA ----
        short8v af0, af1;
        #pragma unroll
        for (int t = 0; t < 2; ++t) {
            short8v f;
            #pragma unroll
            for (int e = 0; e < 8; ++e) {
                const uint2 pk = sw1[t*32 + g*8 + e];
                const float wx = __uint_as_float(pk.x << 16);
                const float wy = __uint_as_float(pk.x & 0xffff0000u);
                const float wz = __uint_as_float(pk.y << 16);
                const float bb = __uint_as_float(pk.y & 0xffff0000u);
                float h = bb + p0*wx + p1*wy + p2*wz;
                h = ELU(h);
                f[e] = f2bf(h);
            }
            if (t == 0) af0 = f; else af1 = f;
        }
        f32x4 hacc[4];
        #pragma unroll
        for (int nt = 0; nt < 4; ++nt) {
            f32x4 a; a[0] = b2c[nt]; a[1] = b2c[nt]; a[2] = b2c[nt]; a[3] = b2c[nt];
            const short8v bf0 = *(const short8v*)&sw2[((nt*2 + 0)*64 + lane) * 8];
            const short8v bf1 = *(const short8v*)&sw2[((nt*2 + 1)*64 + lane) * 8];
            a = MFMA32(af0, bf0, a);
            a = MFMA32(af1, bf1, a);
            hacc[nt] = a;
        }
        short8v a2 = (short8v)0;
        a2[0] = f2bf(xv.x); a2[1] = f2bf(xv.y);
        a2[2] = f2bf(xv.z); a2[3] = f2bf(xv.w);

        // ---- phase B+C fused per 16-col tile u ----
        #pragma unroll
        for (int u = 0; u < 8; ++u) {
            short8v bfrag = (short8v)0;
            if (u < 4) {
                #pragma unroll
                for (int q = 0; q < 4; ++q) bfrag[q] = f2bf(ELU(hacc[u][q]));
            } else {
                #pragma unroll
                for (int e = 0; e < 4; ++e) bfrag[e] = f2bf(fr[(u-4)*4 + e]);
            }
            f32x4 z; z[0] = 0.f; z[1] = 0.f; z[2] = 0.f; z[3] = 0.f;
            const f32x4 fx = MFMA32(a2, bfrag, z);   // fts_X[4g+q][u*16+s]

            const int c = u*16 + s;
            const int wo = c*10 + 2*g;               // stride-10: banks (10s+2g)%32, all 32 used
            const uint2 wm0 = *(const uint2*)&swdwp[wo];
            const uint2 wm1 = *(const uint2*)&swdwp[1280 + wo];
            const float a0 = __uint_as_float(wm0.x << 16);
            const float a1 = __uint_as_float(wm0.x & 0xffff0000u);
            const float a2f = __uint_as_float(wm0.y << 16);
            const float a3 = __uint_as_float(wm0.y & 0xffff0000u);
            const float c0 = __uint_as_float(wm1.x << 16);
            const float c1 = __uint_as_float(wm1.x & 0xffff0000u);
            const float c2 = __uint_as_float(wm1.y << 16);
            const float c3 = __uint_as_float(wm1.y & 0xffff0000u);
            float q0 = fx[0]*a0 + fx[1]*a1 + fx[2]*a2f + fx[3]*a3;
            float q1 = fx[0]*c0 + fx[1]*c1 + fx[2]*c2 + fx[3]*c3;
            q0 += __shfl_xor(q0, 16); q0 += __shfl_xor(q0, 32);
            q1 += __shfl_xor(q1, 16); q1 += __shfl_xor(q1, 32);
            if (lane < 16) {
                float2 r; r.x = q0 + sbdw[2*c]; r.y = q1 + sbdw[2*c + 1];
                *(float2*)&xbuf[(size_t)pt*256 + 2*c] = r;
            }
        }
    }
}

// ---------------- Kernel 3: out = elu(tmp @ wpw^T + bpw) via MFMA (unchanged) ----------------
__global__ __launch_bounds__(256) void k_out(
    const float* __restrict__ tmp, const float* __restrict__ wpw,
    const float* __restrict__ bpw, float* __restrict__ out)
{
    __shared__ unsigned sb[16384];   // 64KB: [n][chunk cb^(n&7)][wi]
    const int tid = threadIdx.x;
    for (int e = tid; e < 16384; e += 256) {
        const int n = e >> 7, kw = e & 127;
        const int cb = kw >> 2, wi = kw & 3;
        const unsigned lo = (unsigned)(unsigned short)f2bf(wpw[n*256 + 2*kw]);
        const unsigned hi = (unsigned)(unsigned short)f2bf(wpw[n*256 + 2*kw + 1]);
        sb[n*128 + ((cb ^ (n & 7)) << 2) + wi] = lo | (hi << 16);
    }
    __syncthreads();

    const int lane = tid & 63, wave = tid >> 6;
    const int g = lane >> 4, s = lane & 15;
    const int row = blockIdx.x * 64 + wave * 16 + s;

    f32x4 acc[8];
    #pragma unroll
    for (int nt = 0; nt < 8; ++nt) {
        const float b = bpw[nt*16 + s];
        acc[nt][0] = b; acc[nt][1] = b; acc[nt][2] = b; acc[nt][3] = b;
    }

    const float* arow = tmp + (size_t)row * 256 + g*8;
    float4 pa0 = *(const float4*)(arow);
    float4 pa1 = *(const float4*)(arow + 4);

    #pragma unroll
    for (int kk = 0; kk < 8; ++kk) {
        const float4 a0 = pa0, a1 = pa1;
        if (kk < 7) {
            pa0 = *(const float4*)(arow + (kk+1)*32);
            pa1 = *(const float4*)(arow + (kk+1)*32 + 4);
        }
        short8v ah, al;
        const float av[8] = {a0.x, a0.y, a0.z, a0.w, a1.x, a1.y, a1.z, a1.w};
        #pragma unroll
        for (int e = 0; e < 8; ++e) {
            const short h = f2bf(av[e]);
            ah[e] = h;
            al[e] = f2bf(av[e] - bf2f(h));
        }
        #pragma unroll
        for (int nt = 0; nt < 8; ++nt) {
            const short8v bf = *(const short8v*)&sb[(nt*16 + s)*128 + (((kk*4 + g) ^ (s & 7)) << 2)];
            acc[nt] = MFMA32(ah, bf, acc[nt]);
            acc[nt] = MFMA32(al, bf, acc[nt]);
        }
    }
    const int rbase = blockIdx.x * 64 + wave * 16 + 4*g;
    #pragma unroll
    for (int nt = 0; nt < 8; ++nt)
        #pragma unroll
        for (int q = 0; q < 4; ++q)
            out[(size_t)(rbase + q) * 128 + nt*16 + s] = ELU(acc[nt][q]);
}

extern "C" void kernel_launch(void* const* d_in, const int* in_sizes, int n_in,
                              void* d_out, int out_size, void* d_ws, size_t ws_size,
                              hipStream_t stream)
{
    (void)in_sizes; (void)n_in; (void)out_size; (void)ws_size;
    const float* rep   = (const float*)d_in[0];
    const float* pts   = (const float*)d_in[1];
    const float* fts   = (const float*)d_in[2];
    const float* w1    = (const float*)d_in[3];
    const float* b1    = (const float*)d_in[4];
    const float* w2    = (const float*)d_in[5];
    const float* b2    = (const float*)d_in[6];
    const float* wconv = (const float*)d_in[7];
    const float* bconv = (const float*)d_in[8];
    const float* wdep1 = (const float*)d_in[9];
    const float* bdep1 = (const float*)d_in[10];
    const float* wdep2 = (const float*)d_in[11];
    const float* bdep2 = (const float*)d_in[12];
    const float* wdw   = (const float*)d_in[13];
    const float* bdw   = (const float*)d_in[14];
    const float* wpw   = (const float*)d_in[15];
    const float* bpw   = (const float*)d_in[16];
    float* out  = (float*)d_out;
    float* xbuf = (float*)d_ws;   // 32768*256 floats = 33.5 MB

    hipFuncSetAttribute((const void*)k_xform, hipFuncAttributeMaxDynamicSharedMemorySize, XW_TOTAL*4);

    k_xform<<<dim3(512),  dim3(256), XW_TOTAL*4, stream>>>(rep, pts, wconv, bconv, wdep1, bdep1, wdep2, bdep2, xbuf);
    k_feat <<<dim3(1024), dim3(256), 0, stream>>>(rep, pts, fts, w1, b1, w2, b2, wdw, bdw, xbuf);
    k_out  <<<dim3(512),  dim3(256), 0, stream>>>(xbuf, wpw, bpw, out);
}

// Round 9
// 239.075 us; speedup vs baseline: 1.2377x; 1.0259x over previous
//
#include <hip/hip_runtime.h>
#include <hip/hip_bf16.h>

// XConv: N=32 P=1024 K=16 DIMS=3 C_IN=64 C_MID=64 C_OUT=128 DM=2; NP=32768
// ws: 32768*256 floats (33.5 MB): holds X2 (untransposed), overwritten in-place by tmp.

#define ELU(x) ((x) > 0.0f ? (x) : (__expf(x) - 1.0f))

__device__ __forceinline__ void lds_fence() {
    asm volatile("s_waitcnt lgkmcnt(0)" ::: "memory");
}

typedef __attribute__((ext_vector_type(8))) short short8v;
typedef __attribute__((ext_vector_type(4))) float f32x4;
#define MFMA32(a, b, c) __builtin_amdgcn_mfma_f32_16x16x32_bf16(a, b, c, 0, 0, 0)

__device__ __forceinline__ short f2bf(float x) {
    __hip_bfloat16 h = __float2bfloat16(x);
    return *reinterpret_cast<short*>(&h);
}
__device__ __forceinline__ float bf2f(short x) {
    unsigned u = ((unsigned)(unsigned short)x) << 16;
    return __uint_as_float(u);
}

// ---------------- Kernel 1: X-transform via MFMA (unchanged) ----------------
#define XW_WC   0        // bf16 frag entries: idx=(part*16+u)*64+lane, 16B each (8192 words)
#define XW_WD1  8192     // wdep1: i*260 + j*16 + k  (4160 words)
#define XW_WD2  12352    // wdep2 same               (4160)
#define XW_BC   16512    // bconv 256
#define XW_BD1  16768    // 256
#define XW_BD2  17024    // 256
#define XW_SCR  17280    // + wave*4368 : per-point stride 273, scr[p*273 + j*17 + s]
#define XW_TOTAL (17280 + 4*4368)   // 34752 words = 139008 B

__global__ __launch_bounds__(256) void k_xform(
    const float* __restrict__ rep, const float* __restrict__ pts,
    const float* __restrict__ wconv, const float* __restrict__ bconv,
    const float* __restrict__ wdep1, const float* __restrict__ bdep1,
    const float* __restrict__ wdep2, const float* __restrict__ bdep2,
    float* __restrict__ x2)
{
    extern __shared__ __align__(16) float sm[];
    short* smh = (short*)sm;
    const int tid = threadIdx.x;

    for (int e = tid; e < 2048; e += 256) {
        const int part = e >> 10, u = (e >> 6) & 15, l = e & 63;
        const int g = l >> 4, s = l & 15;
        const int o = u * 16 + s;
        short8v v;
        if (part == 0) {
            #pragma unroll
            for (int t = 0; t < 8; ++t) v[t] = f2bf(wconv[o*48 + g*8 + t]);
        } else {
            #pragma unroll
            for (int t = 0; t < 4; ++t) v[t] = f2bf(wconv[o*48 + 32 + g*4 + t]);
            #pragma unroll
            for (int t = 4; t < 8; ++t) v[t] = 0;
        }
        *(short8v*)&smh[e * 8] = v;
    }
    for (int e = tid; e < 4096; e += 256) {
        const int i = e >> 8, j = (e >> 4) & 15, k = e & 15;
        sm[XW_WD1 + i*260 + j*16 + k] = wdep1[e];
        sm[XW_WD2 + i*260 + j*16 + k] = wdep2[e];
    }
    sm[XW_BC  + tid] = bconv[tid];
    sm[XW_BD1 + tid] = bdep1[tid];
    sm[XW_BD2 + tid] = bdep2[tid];
    __syncthreads();

    const int wave = tid >> 6, lane = tid & 63;
    const int g = lane >> 4, s = lane & 15;
    const int pt0 = (blockIdx.x * 4 + wave) * 16;

    const int p = pt0 + s;
    const float r0 = rep[p*3], r1 = rep[p*3+1], r2 = rep[p*3+2];
    short8v ah0, al0, ah1, al1;
    #pragma unroll
    for (int e = 0; e < 8; ++e) {
        const int r = g*8 + e;
        const int d = g >> 1, k = r & 15;
        const float v = pts[p*48 + k*3 + d] - (d == 0 ? r0 : r1);
        const short h = f2bf(v);
        ah0[e] = h; al0[e] = f2bf(v - bf2f(h));
    }
    #pragma unroll
    for (int e = 0; e < 4; ++e) {
        const int k = g*4 + e;
        const float v = pts[p*48 + k*3 + 2] - r2;
        const short h = f2bf(v);
        ah1[e] = h; al1[e] = f2bf(v - bf2f(h));
    }
    #pragma unroll
    for (int e = 4; e < 8; ++e) { ah1[e] = 0; al1[e] = 0; }

    f32x4 ex[16];
    #pragma unroll
    for (int u = 0; u < 16; ++u) {
        const float b = sm[XW_BC + u*16 + s];
        f32x4 acc; acc[0] = b; acc[1] = b; acc[2] = b; acc[3] = b;
        const short8v bh0 = *(const short8v*)&smh[(u*64 + lane) * 8];
        const short8v bh1 = *(const short8v*)&smh[((16 + u)*64 + lane) * 8];
        acc = MFMA32(ah0, bh0, acc);
        acc = MFMA32(ah1, bh1, acc);
        acc = MFMA32(al0, bh0, acc);
        acc = MFMA32(al1, bh1, acc);
        f32x4 r;
        r[0] = ELU(acc[0]); r[1] = ELU(acc[1]); r[2] = ELU(acc[2]); r[3] = ELU(acc[3]);
        ex[u] = r;
    }

    const int scrb = XW_SCR + wave * 4368;
    #pragma unroll
    for (int j = 0; j < 16; ++j) {
        const float b = sm[XW_BD1 + s*16 + j];
        f32x4 a; a[0] = b; a[1] = b; a[2] = b; a[3] = b;
        #pragma unroll
        for (int kb = 0; kb < 4; ++kb) {
            const float4 w = *(const float4*)&sm[XW_WD1 + s*260 + j*16 + kb*4];
            a += ex[kb*4+0] * w.x; a += ex[kb*4+1] * w.y;
            a += ex[kb*4+2] * w.z; a += ex[kb*4+3] * w.w;
        }
        #pragma unroll
        for (int q = 0; q < 4; ++q)
            sm[scrb + (g*4+q)*273 + j*17 + s] = ELU(a[q]);
    }
    lds_fence();

    f32x4 xr[16];
    #pragma unroll
    for (int k = 0; k < 16; ++k) {
        f32x4 v;
        #pragma unroll
        for (int q = 0; q < 4; ++q)
            v[q] = sm[scrb + (g*4+q)*273 + s*17 + k];
        xr[k] = v;
    }
    f32x4 oj[16];
    #pragma unroll
    for (int j = 0; j < 16; ++j) {
        const float b = sm[XW_BD2 + s*16 + j];
        f32x4 a; a[0] = b; a[1] = b; a[2] = b; a[3] = b;
        #pragma unroll
        for (int kb = 0; kb < 4; ++kb) {
            const float4 w = *(const float4*)&sm[XW_WD2 + s*260 + j*16 + kb*4];
            a += xr[kb*4+0] * w.x; a += xr[kb*4+1] * w.y;
            a += xr[kb*4+2] * w.z; a += xr[kb*4+3] * w.w;
        }
        oj[j] = a;
    }
    #pragma unroll
    for (int q = 0; q < 4; ++q) {
        const int pp = pt0 + g*4 + q;
        #pragma unroll
        for (int jb = 0; jb < 4; ++jb) {
            *(float4*)&x2[pp*256 + s*16 + jb*4] =
                make_float4(oj[jb*4+0][q], oj[jb*4+1][q], oj[jb*4+2][q], oj[jb*4+3][q]);
        }
    }
}

// ---------------- Kernel 2: MFMA features; LDS weights; no prefetch; (256,3) reg tier ----
// 8 points/wave. Cap history: no-cap -> 128+acc, 2 waves/SIMD, latency-bound (R3 105us);
// cap 128 total -> ~20 words/lane spilled every iter (R7/R8, FETCH 3x). Cap 170 (256,3):
// peak ~80 arch + ~24 acc fits with headroom -> no spill AND 3 waves/SIMD.
__global__ __launch_bounds__(256, 3) void k_feat(
    const float* __restrict__ rep, const float* __restrict__ pts, const float* __restrict__ fts,
    const float* __restrict__ w1, const float* __restrict__ b1,
    const float* __restrict__ w2, const float* __restrict__ b2,
    const float* __restrict__ wdw, const float* __restrict__ bdw,
    float* __restrict__ xbuf)
{
    __shared__ __align__(16) short sw2[4096];      // B-frags: rec r=nt*2+h, 16B @ (r*64+lane)
    __shared__ __align__(16) uint2 sw1[64];        // j: {pack(w1[0][j],w1[1][j]), pack(w1[2][j],b1[j])}
    __shared__ __align__(16) unsigned swdwp[2560]; // [m][c] stride 10 (all-32-bank b64 reads)
    __shared__ float sbdw[256];
    const int tid = threadIdx.x;

    for (int idx = tid; idx < 512; idx += 256) {   // 512 recs of 8 bf16
        const int r = idx >> 6, l = idx & 63;
        const int nt = r >> 1, h = r & 1, gg = l >> 4, ss = l & 15;
        short8v v;
        #pragma unroll
        for (int e = 0; e < 8; ++e)
            v[e] = f2bf(w2[(h*32 + gg*8 + e)*64 + nt*16 + ss]);
        *(short8v*)&sw2[idx * 8] = v;
    }
    if (tid < 64) {
        const int j = tid;
        uint2 v;
        v.x = (unsigned)(unsigned short)f2bf(w1[j])
            | (((unsigned)(unsigned short)f2bf(w1[64 + j])) << 16);
        v.y = (unsigned)(unsigned short)f2bf(w1[128 + j])
            | (((unsigned)(unsigned short)f2bf(b1[j])) << 16);
        sw1[j] = v;
    }
    for (int e = tid; e < 2048; e += 256) {
        const int m = e >> 10, c = (e >> 3) & 127, w = e & 7;
        const unsigned lo = (unsigned)(unsigned short)f2bf(wdw[c*32 + m*16 + 2*w]);
        const unsigned hi = (unsigned)(unsigned short)f2bf(wdw[c*32 + m*16 + 2*w + 1]);
        swdwp[m*1280 + c*10 + w] = lo | (hi << 16);
    }
    sbdw[tid] = bdw[tid];
    __syncthreads();

    const int lane = tid & 63, wave = tid >> 6;
    const int g = lane >> 4, s = lane & 15;

    float b2c[4];
    #pragma unroll
    for (int nt = 0; nt < 4; ++nt) b2c[nt] = b2[nt*16 + s];

    const int pt0 = (blockIdx.x * 4 + wave) * 8;

    for (int it = 0; it < 8; ++it) {
        const int pt = pt0 + it;

        // ---- issue all global loads for this point (coalesced 64B segments over s) ----
        float fr[16];
        #pragma unroll
        for (int ct = 0; ct < 4; ++ct)
            #pragma unroll
            for (int e = 0; e < 4; ++e)
                fr[ct*4+e] = fts[(size_t)pt*1024 + (g*4 + e)*64 + ct*16 + s];
        const float4 xv = *(const float4*)&xbuf[(size_t)pt*256 + s*16 + g*4];
        const float p0 = pts[pt*48 + s*3 + 0] - rep[pt*3 + 0];
        const float p1 = pts[pt*48 + s*3 + 1] - rep[pt*3 + 1];
        const float p2 = pts[pt*48 + s*3 + 2] - rep[pt*3 + 2];

        // ---- phase A: h1 (w1/b1 broadcast from LDS) in A-frag layout; h2 via 8 MFMA ----
        short8v af0, af1;
        #pragma unroll
        for (int t = 0; t < 2; ++t) {
            short8v f;
            #pragma unroll
            for (int e = 0; e < 8; ++e) {
                const uint2 pk = sw1[t*32 + g*8 + e];
                const float wx = __uint_as_float(pk.x << 16);
                const float wy = __uint_as_float(pk.x & 0xffff0000u);
                const float wz = __uint_as_float(pk.y << 16);
                const float bb = __uint_as_float(pk.y & 0xffff0000u);
                float h = bb + p0*wx + p1*wy + p2*wz;
                h = ELU(h);
                f[e] = f2bf(h);
            }
            if (t == 0) af0 = f; else af1 = f;
        }
        f32x4 hacc[4];
        #pragma unroll
        for (int nt = 0; nt < 4; ++nt) {
            f32x4 a; a[0] = b2c[nt]; a[1] = b2c[nt]; a[2] = b2c[nt]; a[3] = b2c[nt];
            const short8v bf0 = *(const short8v*)&sw2[((nt*2 + 0)*64 + lane) * 8];
            const short8v bf1 = *(const short8v*)&sw2[((nt*2 + 1)*64 + lane) * 8];
            a = MFMA32(af0, bf0, a);
            a = MFMA32(af1, bf1, a);
            hacc[nt] = a;
        }
        short8v a2 = (short8v)0;
        a2[0] = f2bf(xv.x); a2[1] = f2bf(xv.y);
        a2[2] = f2bf(xv.z); a2[3] = f2bf(xv.w);

        // ---- phase B+C fused per 16-col tile u ----
        #pragma unroll
        for (int u = 0; u < 8; ++u) {
            short8v bfrag = (short8v)0;
            if (u < 4) {
                #pragma unroll
                for (int q = 0; q < 4; ++q) bfrag[q] = f2bf(ELU(hacc[u][q]));
            } else {
                #pragma unroll
                for (int e = 0; e < 4; ++e) bfrag[e] = f2bf(fr[(u-4)*4 + e]);
            }
            f32x4 z; z[0] = 0.f; z[1] = 0.f; z[2] = 0.f; z[3] = 0.f;
            const f32x4 fx = MFMA32(a2, bfrag, z);   // fts_X[4g+q][u*16+s]

            const int c = u*16 + s;
            const int wo = c*10 + 2*g;               // stride-10: banks (10s+2g)%32, all 32 used
            const uint2 wm0 = *(const uint2*)&swdwp[wo];
            const uint2 wm1 = *(const uint2*)&swdwp[1280 + wo];
            const float a0 = __uint_as_float(wm0.x << 16);
            const float a1 = __uint_as_float(wm0.x & 0xffff0000u);
            const float a2f = __uint_as_float(wm0.y << 16);
            const float a3 = __uint_as_float(wm0.y & 0xffff0000u);
            const float c0 = __uint_as_float(wm1.x << 16);
            const float c1 = __uint_as_float(wm1.x & 0xffff0000u);
            const float c2 = __uint_as_float(wm1.y << 16);
            const float c3 = __uint_as_float(wm1.y & 0xffff0000u);
            float q0 = fx[0]*a0 + fx[1]*a1 + fx[2]*a2f + fx[3]*a3;
            float q1 = fx[0]*c0 + fx[1]*c1 + fx[2]*c2 + fx[3]*c3;
            q0 += __shfl_xor(q0, 16); q0 += __shfl_xor(q0, 32);
            q1 += __shfl_xor(q1, 16); q1 += __shfl_xor(q1, 32);
            if (lane < 16) {
                float2 r; r.x = q0 + sbdw[2*c]; r.y = q1 + sbdw[2*c + 1];
                *(float2*)&xbuf[(size_t)pt*256 + 2*c] = r;
            }
        }
    }
}

// ---------------- Kernel 3: out = elu(tmp @ wpw^T + bpw) via MFMA (unchanged) ----------------
__global__ __launch_bounds__(256) void k_out(
    const float* __restrict__ tmp, const float* __restrict__ wpw,
    const float* __restrict__ bpw, float* __restrict__ out)
{
    __shared__ unsigned sb[16384];   // 64KB: [n][chunk cb^(n&7)][wi]
    const int tid = threadIdx.x;
    for (int e = tid; e < 16384; e += 256) {
        const int n = e >> 7, kw = e & 127;
        const int cb = kw >> 2, wi = kw & 3;
        const unsigned lo = (unsigned)(unsigned short)f2bf(wpw[n*256 + 2*kw]);
        const unsigned hi = (unsigned)(unsigned short)f2bf(wpw[n*256 + 2*kw + 1]);
        sb[n*128 + ((cb ^ (n & 7)) << 2) + wi] = lo | (hi << 16);
    }
    __syncthreads();

    const int lane = tid & 63, wave = tid >> 6;
    const int g = lane >> 4, s = lane & 15;
    const int row = blockIdx.x * 64 + wave * 16 + s;

    f32x4 acc[8];
    #pragma unroll
    for (int nt = 0; nt < 8; ++nt) {
        const float b = bpw[nt*16 + s];
        acc[nt][0] = b; acc[nt][1] = b; acc[nt][2] = b; acc[nt][3] = b;
    }

    const float* arow = tmp + (size_t)row * 256 + g*8;
    float4 pa0 = *(const float4*)(arow);
    float4 pa1 = *(const float4*)(arow + 4);

    #pragma unroll
    for (int kk = 0; kk < 8; ++kk) {
        const float4 a0 = pa0, a1 = pa1;
        if (kk < 7) {
            pa0 = *(const float4*)(arow + (kk+1)*32);
            pa1 = *(const float4*)(arow + (kk+1)*32 + 4);
        }
        short8v ah, al;
        const float av[8] = {a0.x, a0.y, a0.z, a0.w, a1.x, a1.y, a1.z, a1.w};
        #pragma unroll
        for (int e = 0; e < 8; ++e) {
            const short h = f2bf(av[e]);
            ah[e] = h;
            al[e] = f2bf(av[e] - bf2f(h));
        }
        #pragma unroll
        for (int nt = 0; nt < 8; ++nt) {
            const short8v bf = *(const short8v*)&sb[(nt*16 + s)*128 + (((kk*4 + g) ^ (s & 7)) << 2)];
            acc[nt] = MFMA32(ah, bf, acc[nt]);
            acc[nt] = MFMA32(al, bf, acc[nt]);
        }
    }
    const int rbase = blockIdx.x * 64 + wave * 16 + 4*g;
    #pragma unroll
    for (int nt = 0; nt < 8; ++nt)
        #pragma unroll
        for (int q = 0; q < 4; ++q)
            out[(size_t)(rbase + q) * 128 + nt*16 + s] = ELU(acc[nt][q]);
}

extern "C" void kernel_launch(void* const* d_in, const int* in_sizes, int n_in,
                              void* d_out, int out_size, void* d_ws, size_t ws_size,
                              hipStream_t stream)
{
    (void)in_sizes; (void)n_in; (void)out_size; (void)ws_size;
    const float* rep   = (const float*)d_in[0];
    const float* pts   = (const float*)d_in[1];
    const float* fts   = (const float*)d_in[2];
    const float* w1    = (const float*)d_in[3];
    const float* b1    = (const float*)d_in[4];
    const float* w2    = (const float*)d_in[5];
    const float* b2    = (const float*)d_in[6];
    const float* wconv = (const float*)d_in[7];
    const float* bconv = (const float*)d_in[8];
    const float* wdep1 = (const float*)d_in[9];
    const float* bdep1 = (const float*)d_in[10];
    const float* wdep2 = (const float*)d_in[11];
    const float* bdep2 = (const float*)d_in[12];
    const float* wdw   = (const float*)d_in[13];
    const float* bdw   = (const float*)d_in[14];
    const float* wpw   = (const float*)d_in[15];
    const float* bpw   = (const float*)d_in[16];
    float* out  = (float*)d_out;
    float* xbuf = (float*)d_ws;   // 32768*256 floats = 33.5 MB

    hipFuncSetAttribute((const void*)k_xform, hipFuncAttributeMaxDynamicSharedMemorySize, XW_TOTAL*4);

    k_xform<<<dim3(512),  dim3(256), XW_TOTAL*4, stream>>>(rep, pts, wconv, bconv, wdep1, bdep1, wdep2, bdep2, xbuf);
    k_feat <<<dim3(1024), dim3(256), 0, stream>>>(rep, pts, fts, w1, b1, w2, b2, wdw, bdw, xbuf);
    k_out  <<<dim3(512),  dim3(256), 0, stream>>>(xbuf, wpw, bpw, out);
}

// Round 10
// 111.533 us; speedup vs baseline: 2.6531x; 2.1435x over previous
//
#include <hip/hip_runtime.h>
#include <hip/hip_bf16.h>

// XConv: N=32 P=1024 K=16 DIMS=3 C_IN=64 C_MID=64 C_OUT=128 DM=2; NP=32768
// ws: 32768*256 floats (33.5 MB): holds X2 (untransposed), overwritten in-place by tmp.

#define ELU(x) ((x) > 0.0f ? (x) : (__expf(x) - 1.0f))

__device__ __forceinline__ void lds_fence() {
    asm volatile("s_waitcnt lgkmcnt(0)" ::: "memory");
}

typedef __attribute__((ext_vector_type(8))) short short8v;
typedef __attribute__((ext_vector_type(4))) float f32x4;
#define MFMA32(a, b, c) __builtin_amdgcn_mfma_f32_16x16x32_bf16(a, b, c, 0, 0, 0)

__device__ __forceinline__ short f2bf(float x) {
    __hip_bfloat16 h = __float2bfloat16(x);
    return *reinterpret_cast<short*>(&h);
}
__device__ __forceinline__ float bf2f(short x) {
    unsigned u = ((unsigned)(unsigned short)x) << 16;
    return __uint_as_float(u);
}
__device__ __forceinline__ void gload_lds16(const float* g, float* l) {
    __builtin_amdgcn_global_load_lds(
        (const __attribute__((address_space(1))) void*)g,
        (__attribute__((address_space(3))) void*)l,
        16, 0, 0);
}

// ---------------- Kernel 1: X-transform via MFMA (unchanged) ----------------
#define XW_WC   0        // bf16 frag entries: idx=(part*16+u)*64+lane, 16B each (8192 words)
#define XW_WD1  8192     // wdep1: i*260 + j*16 + k  (4160 words)
#define XW_WD2  12352    // wdep2 same               (4160)
#define XW_BC   16512    // bconv 256
#define XW_BD1  16768    // 256
#define XW_BD2  17024    // 256
#define XW_SCR  17280    // + wave*4368 : per-point stride 273, scr[p*273 + j*17 + s]
#define XW_TOTAL (17280 + 4*4368)   // 34752 words = 139008 B

__global__ __launch_bounds__(256) void k_xform(
    const float* __restrict__ rep, const float* __restrict__ pts,
    const float* __restrict__ wconv, const float* __restrict__ bconv,
    const float* __restrict__ wdep1, const float* __restrict__ bdep1,
    const float* __restrict__ wdep2, const float* __restrict__ bdep2,
    float* __restrict__ x2)
{
    extern __shared__ __align__(16) float sm[];
    short* smh = (short*)sm;
    const int tid = threadIdx.x;

    for (int e = tid; e < 2048; e += 256) {
        const int part = e >> 10, u = (e >> 6) & 15, l = e & 63;
        const int g = l >> 4, s = l & 15;
        const int o = u * 16 + s;
        short8v v;
        if (part == 0) {
            #pragma unroll
            for (int t = 0; t < 8; ++t) v[t] = f2bf(wconv[o*48 + g*8 + t]);
        } else {
            #pragma unroll
            for (int t = 0; t < 4; ++t) v[t] = f2bf(wconv[o*48 + 32 + g*4 + t]);
            #pragma unroll
            for (int t = 4; t < 8; ++t) v[t] = 0;
        }
        *(short8v*)&smh[e * 8] = v;
    }
    for (int e = tid; e < 4096; e += 256) {
        const int i = e >> 8, j = (e >> 4) & 15, k = e & 15;
        sm[XW_WD1 + i*260 + j*16 + k] = wdep1[e];
        sm[XW_WD2 + i*260 + j*16 + k] = wdep2[e];
    }
    sm[XW_BC  + tid] = bconv[tid];
    sm[XW_BD1 + tid] = bdep1[tid];
    sm[XW_BD2 + tid] = bdep2[tid];
    __syncthreads();

    const int wave = tid >> 6, lane = tid & 63;
    const int g = lane >> 4, s = lane & 15;
    const int pt0 = (blockIdx.x * 4 + wave) * 16;

    const int p = pt0 + s;
    const float r0 = rep[p*3], r1 = rep[p*3+1], r2 = rep[p*3+2];
    short8v ah0, al0, ah1, al1;
    #pragma unroll
    for (int e = 0; e < 8; ++e) {
        const int r = g*8 + e;
        const int d = g >> 1, k = r & 15;
        const float v = pts[p*48 + k*3 + d] - (d == 0 ? r0 : r1);
        const short h = f2bf(v);
        ah0[e] = h; al0[e] = f2bf(v - bf2f(h));
    }
    #pragma unroll
    for (int e = 0; e < 4; ++e) {
        const int k = g*4 + e;
        const float v = pts[p*48 + k*3 + 2] - r2;
        const short h = f2bf(v);
        ah1[e] = h; al1[e] = f2bf(v - bf2f(h));
    }
    #pragma unroll
    for (int e = 4; e < 8; ++e) { ah1[e] = 0; al1[e] = 0; }

    f32x4 ex[16];
    #pragma unroll
    for (int u = 0; u < 16; ++u) {
        const float b = sm[XW_BC + u*16 + s];
        f32x4 acc; acc[0] = b; acc[1] = b; acc[2] = b; acc[3] = b;
        const short8v bh0 = *(const short8v*)&smh[(u*64 + lane) * 8];
        const short8v bh1 = *(const short8v*)&smh[((16 + u)*64 + lane) * 8];
        acc = MFMA32(ah0, bh0, acc);
        acc = MFMA32(ah1, bh1, acc);
        acc = MFMA32(al0, bh0, acc);
        acc = MFMA32(al1, bh1, acc);
        f32x4 r;
        r[0] = ELU(acc[0]); r[1] = ELU(acc[1]); r[2] = ELU(acc[2]); r[3] = ELU(acc[3]);
        ex[u] = r;
    }

    const int scrb = XW_SCR + wave * 4368;
    #pragma unroll
    for (int j = 0; j < 16; ++j) {
        const float b = sm[XW_BD1 + s*16 + j];
        f32x4 a; a[0] = b; a[1] = b; a[2] = b; a[3] = b;
        #pragma unroll
        for (int kb = 0; kb < 4; ++kb) {
            const float4 w = *(const float4*)&sm[XW_WD1 + s*260 + j*16 + kb*4];
            a += ex[kb*4+0] * w.x; a += ex[kb*4+1] * w.y;
            a += ex[kb*4+2] * w.z; a += ex[kb*4+3] * w.w;
        }
        #pragma unroll
        for (int q = 0; q < 4; ++q)
            sm[scrb + (g*4+q)*273 + j*17 + s] = ELU(a[q]);
    }
    lds_fence();

    f32x4 xr[16];
    #pragma unroll
    for (int k = 0; k < 16; ++k) {
        f32x4 v;
        #pragma unroll
        for (int q = 0; q < 4; ++q)
            v[q] = sm[scrb + (g*4+q)*273 + s*17 + k];
        xr[k] = v;
    }
    f32x4 oj[16];
    #pragma unroll
    for (int j = 0; j < 16; ++j) {
        const float b = sm[XW_BD2 + s*16 + j];
        f32x4 a; a[0] = b; a[1] = b; a[2] = b; a[3] = b;
        #pragma unroll
        for (int kb = 0; kb < 4; ++kb) {
            const float4 w = *(const float4*)&sm[XW_WD2 + s*260 + j*16 + kb*4];
            a += xr[kb*4+0] * w.x; a += xr[kb*4+1] * w.y;
            a += xr[kb*4+2] * w.z; a += xr[kb*4+3] * w.w;
        }
        oj[j] = a;
    }
    #pragma unroll
    for (int q = 0; q < 4; ++q) {
        const int pp = pt0 + g*4 + q;
        #pragma unroll
        for (int jb = 0; jb < 4; ++jb) {
            *(float4*)&x2[pp*256 + s*16 + jb*4] =
                make_float4(oj[jb*4+0][q], oj[jb*4+1][q], oj[jb*4+2][q], oj[jb*4+3][q]);
        }
    }
}

// ---------------- Kernel 2: MFMA features; fts via double-buffered global_load_lds ----------
// 8 points/wave. Per iter: scalar loads(pt) -> DMA(pt+1) issue -> phase A -> vmcnt(4) (in-order
// retire => DMA(pt) done) -> phase B reads LDS. Linear src+dest DMA (R4's overfetch was from
// swizzled src). Register demand ~55 arch + 16 acc -> no spills at (256,3); LDS 51.5KB/block.
__global__ __launch_bounds__(256, 3) void k_feat(
    const float* __restrict__ rep, const float* __restrict__ pts, const float* __restrict__ fts,
    const float* __restrict__ w1, const float* __restrict__ b1,
    const float* __restrict__ w2, const float* __restrict__ b2,
    const float* __restrict__ wdw, const float* __restrict__ bdw,
    float* __restrict__ xbuf)
{
    __shared__ __align__(16) short sw2[4096];      // B-frags: rec r=nt*2+h, 16B @ (r*64+lane)
    __shared__ __align__(16) uint2 sw1[64];        // j: {pack(w1[0][j],w1[1][j]), pack(w1[2][j],b1[j])}
    __shared__ __align__(16) unsigned swdwp[2560]; // [m][c] stride 10 (all-32-bank b64 reads)
    __shared__ float sbdw[256];
    __shared__ __align__(16) float sfts[4][2][1024]; // [wave][buf][fts point tile], 32KB
    const int tid = threadIdx.x;

    for (int idx = tid; idx < 512; idx += 256) {   // 512 recs of 8 bf16
        const int r = idx >> 6, l = idx & 63;
        const int nt = r >> 1, h = r & 1, gg = l >> 4, ss = l & 15;
        short8v v;
        #pragma unroll
        for (int e = 0; e < 8; ++e)
            v[e] = f2bf(w2[(h*32 + gg*8 + e)*64 + nt*16 + ss]);
        *(short8v*)&sw2[idx * 8] = v;
    }
    if (tid < 64) {
        const int j = tid;
        uint2 v;
        v.x = (unsigned)(unsigned short)f2bf(w1[j])
            | (((unsigned)(unsigned short)f2bf(w1[64 + j])) << 16);
        v.y = (unsigned)(unsigned short)f2bf(w1[128 + j])
            | (((unsigned)(unsigned short)f2bf(b1[j])) << 16);
        sw1[j] = v;
    }
    for (int e = tid; e < 2048; e += 256) {
        const int m = e >> 10, c = (e >> 3) & 127, w = e & 7;
        const unsigned lo = (unsigned)(unsigned short)f2bf(wdw[c*32 + m*16 + 2*w]);
        const unsigned hi = (unsigned)(unsigned short)f2bf(wdw[c*32 + m*16 + 2*w + 1]);
        swdwp[m*1280 + c*10 + w] = lo | (hi << 16);
    }
    sbdw[tid] = bdw[tid];
    __syncthreads();

    const int lane = tid & 63, wave = tid >> 6;
    const int g = lane >> 4, s = lane & 15;

    float b2c[4];
    #pragma unroll
    for (int nt = 0; nt < 4; ++nt) b2c[nt] = b2[nt*16 + s];

    const int pt0 = (blockIdx.x * 4 + wave) * 8;
    float* sf0 = &sfts[wave][0][0];
    float* sf1 = &sfts[wave][1][0];

    // ---- prologue: DMA point pt0 into buf0 (linear src, linear dest) ----
    {
        const float* src = fts + (size_t)pt0 * 1024 + lane * 4;
        #pragma unroll
        for (int i = 0; i < 4; ++i) gload_lds16(src + i*256, sf0 + i*256);
    }

    for (int it = 0; it < 8; ++it) {
        const int pt = pt0 + it;
        float* sfc = (it & 1) ? sf1 : sf0;
        float* sfn = (it & 1) ? sf0 : sf1;

        // ---- scalar loads for pt (issued BEFORE next DMA so compiler waits don't drain it) ----
        const float4 xv = *(const float4*)&xbuf[(size_t)pt*256 + s*16 + g*4];
        const float p0 = pts[pt*48 + s*3 + 0] - rep[pt*3 + 0];
        const float p1 = pts[pt*48 + s*3 + 1] - rep[pt*3 + 1];
        const float p2 = pts[pt*48 + s*3 + 2] - rep[pt*3 + 2];

        // ---- issue DMA for pt+1 ----
        if (it < 7) {
            const float* src = fts + (size_t)(pt + 1) * 1024 + lane * 4;
            #pragma unroll
            for (int i = 0; i < 4; ++i) gload_lds16(src + i*256, sfn + i*256);
        }

        // ---- phase A: h1 (w1/b1 broadcast from LDS) in A-frag layout; h2 via 8 MFMA ----
        short8v af0, af1;
        #pragma unroll
        for (int t = 0; t < 2; ++t) {
            short8v f;
            #pragma unroll
            for (int e = 0; e < 8; ++e) {
                const uint2 pk = sw1[t*32 + g*8 + e];
                const float wx = __uint_as_float(pk.x << 16);
                const float wy = __uint_as_float(pk.x & 0xffff0000u);
                const float wz = __uint_as_float(pk.y << 16);
                const float bb = __uint_as_float(pk.y & 0xffff0000u);
                float h = bb + p0*wx + p1*wy + p2*wz;
                h = ELU(h);
                f[e] = f2bf(h);
            }
            if (t == 0) af0 = f; else af1 = f;
        }
        f32x4 hacc[4];
        #pragma unroll
        for (int nt = 0; nt < 4; ++nt) {
            f32x4 a; a[0] = b2c[nt]; a[1] = b2c[nt]; a[2] = b2c[nt]; a[3] = b2c[nt];
            const short8v bf0 = *(const short8v*)&sw2[((nt*2 + 0)*64 + lane) * 8];
            const short8v bf1 = *(const short8v*)&sw2[((nt*2 + 1)*64 + lane) * 8];
            a = MFMA32(af0, bf0, a);
            a = MFMA32(af1, bf1, a);
            hacc[nt] = a;
        }
        short8v a2 = (short8v)0;
        a2[0] = f2bf(xv.x); a2[1] = f2bf(xv.y);
        a2[2] = f2bf(xv.z); a2[3] = f2bf(xv.w);

        // ---- DMA(pt) retired when outstanding <= 4 (the DMA(pt+1) set; in-order retire) ----
        asm volatile("s_waitcnt vmcnt(4)" ::: "memory");

        // ---- phase B+C fused per 16-col tile u ----
        #pragma unroll
        for (int u = 0; u < 8; ++u) {
            short8v bfrag = (short8v)0;
            if (u < 4) {
                #pragma unroll
                for (int q = 0; q < 4; ++q) bfrag[q] = f2bf(ELU(hacc[u][q]));
            } else {
                #pragma unroll
                for (int e = 0; e < 4; ++e)
                    bfrag[e] = f2bf(sfc[(g*4 + e)*64 + (u - 4)*16 + s]);
            }
            f32x4 z; z[0] = 0.f; z[1] = 0.f; z[2] = 0.f; z[3] = 0.f;
            const f32x4 fx = MFMA32(a2, bfrag, z);   // fts_X[4g+q][u*16+s]

            const int c = u*16 + s;
            const int wo = c*10 + 2*g;               // stride-10: banks (10s+2g)%32, all 32 used
            const uint2 wm0 = *(const uint2*)&swdwp[wo];
            const uint2 wm1 = *(const uint2*)&swdwp[1280 + wo];
            const float a0 = __uint_as_float(wm0.x << 16);
            const float a1 = __uint_as_float(wm0.x & 0xffff0000u);
            const float a2f = __uint_as_float(wm0.y << 16);
            const float a3 = __uint_as_float(wm0.y & 0xffff0000u);
            const float c0 = __uint_as_float(wm1.x << 16);
            const float c1 = __uint_as_float(wm1.x & 0xffff0000u);
            const float c2 = __uint_as_float(wm1.y << 16);
            const float c3 = __uint_as_float(wm1.y & 0xffff0000u);
            float q0 = fx[0]*a0 + fx[1]*a1 + fx[2]*a2f + fx[3]*a3;
            float q1 = fx[0]*c0 + fx[1]*c1 + fx[2]*c2 + fx[3]*c3;
            q0 += __shfl_xor(q0, 16); q0 += __shfl_xor(q0, 32);
            q1 += __shfl_xor(q1, 16); q1 += __shfl_xor(q1, 32);
            if (lane < 16) {
                float2 r; r.x = q0 + sbdw[2*c]; r.y = q1 + sbdw[2*c + 1];
                *(float2*)&xbuf[(size_t)pt*256 + 2*c] = r;
            }
        }
    }
}

// ---------------- Kernel 3: out = elu(tmp @ wpw^T + bpw) via MFMA (unchanged) ----------------
__global__ __launch_bounds__(256) void k_out(
    const float* __restrict__ tmp, const float* __restrict__ wpw,
    const float* __restrict__ bpw, float* __restrict__ out)
{
    __shared__ unsigned sb[16384];   // 64KB: [n][chunk cb^(n&7)][wi]
    const int tid = threadIdx.x;
    for (int e = tid; e < 16384; e += 256) {
        const int n = e >> 7, kw = e & 127;
        const int cb = kw >> 2, wi = kw & 3;
        const unsigned lo = (unsigned)(unsigned short)f2bf(wpw[n*256 + 2*kw]);
        const unsigned hi = (unsigned)(unsigned short)f2bf(wpw[n*256 + 2*kw + 1]);
        sb[n*128 + ((cb ^ (n & 7)) << 2) + wi] = lo | (hi << 16);
    }
    __syncthreads();

    const int lane = tid & 63, wave = tid >> 6;
    const int g = lane >> 4, s = lane & 15;
    const int row = blockIdx.x * 64 + wave * 16 + s;

    f32x4 acc[8];
    #pragma unroll
    for (int nt = 0; nt < 8; ++nt) {
        const float b = bpw[nt*16 + s];
        acc[nt][0] = b; acc[nt][1] = b; acc[nt][2] = b; acc[nt][3] = b;
    }

    const float* arow = tmp + (size_t)row * 256 + g*8;
    float4 pa0 = *(const float4*)(arow);
    float4 pa1 = *(const float4*)(arow + 4);

    #pragma unroll
    for (int kk = 0; kk < 8; ++kk) {
        const float4 a0 = pa0, a1 = pa1;
        if (kk < 7) {
            pa0 = *(const float4*)(arow + (kk+1)*32);
            pa1 = *(const float4*)(arow + (kk+1)*32 + 4);
        }
        short8v ah, al;
        const float av[8] = {a0.x, a0.y, a0.z, a0.w, a1.x, a1.y, a1.z, a1.w};
        #pragma unroll
        for (int e = 0; e < 8; ++e) {
            const short h = f2bf(av[e]);
            ah[e] = h;
            al[e] = f2bf(av[e] - bf2f(h));
        }
        #pragma unroll
        for (int nt = 0; nt < 8; ++nt) {
            const short8v bf = *(const short8v*)&sb[(nt*16 + s)*128 + (((kk*4 + g) ^ (s & 7)) << 2)];
            acc[nt] = MFMA32(ah, bf, acc[nt]);
            acc[nt] = MFMA32(al, bf, acc[nt]);
        }
    }
    const int rbase = blockIdx.x * 64 + wave * 16 + 4*g;
    #pragma unroll
    for (int nt = 0; nt < 8; ++nt)
        #pragma unroll
        for (int q = 0; q < 4; ++q)
            out[(size_t)(rbase + q) * 128 + nt*16 + s] = ELU(acc[nt][q]);
}

extern "C" void kernel_launch(void* const* d_in, const int* in_sizes, int n_in,
                              void* d_out, int out_size, void* d_ws, size_t ws_size,
                              hipStream_t stream)
{
    (void)in_sizes; (void)n_in; (void)out_size; (void)ws_size;
    const float* rep   = (const float*)d_in[0];
    const float* pts   = (const float*)d_in[1];
    const float* fts   = (const float*)d_in[2];
    const float* w1    = (const float*)d_in[3];
    const float* b1    = (const float*)d_in[4];
    const float* w2    = (const float*)d_in[5];
    const float* b2    = (const float*)d_in[6];
    const float* wconv = (const float*)d_in[7];
    const float* bconv = (const float*)d_in[8];
    const float* wdep1 = (const float*)d_in[9];
    const float* bdep1 = (const float*)d_in[10];
    const float* wdep2 = (const float*)d_in[11];
    const float* bdep2 = (const float*)d_in[12];
    const float* wdw   = (const float*)d_in[13];
    const float* bdw   = (const float*)d_in[14];
    const float* wpw   = (const float*)d_in[15];
    const float* bpw   = (const float*)d_in[16];
    float* out  = (float*)d_out;
    float* xbuf = (float*)d_ws;   // 32768*256 floats = 33.5 MB

    hipFuncSetAttribute((const void*)k_xform, hipFuncAttributeMaxDynamicSharedMemorySize, XW_TOTAL*4);

    k_xform<<<dim3(512),  dim3(256), XW_TOTAL*4, stream>>>(rep, pts, wconv, bconv, wdep1, bdep1, wdep2, bdep2, xbuf);
    k_feat <<<dim3(1024), dim3(256), 0, stream>>>(rep, pts, fts, w1, b1, w2, b2, wdw, bdw, xbuf);
    k_out  <<<dim3(512),  dim3(256), 0, stream>>>(xbuf, wpw, bpw, out);
}

// Round 11
// 105.439 us; speedup vs baseline: 2.8065x; 1.0578x over previous
//
#include <hip/hip_runtime.h>
#include <hip/hip_bf16.h>

// XConv: N=32 P=1024 K=16 DIMS=3 C_IN=64 C_MID=64 C_OUT=128 DM=2; NP=32768
// ws: 32768*256 floats (33.5 MB): holds X2 (untransposed), overwritten in-place by tmp.

#define ELU(x) ((x) > 0.0f ? (x) : (__expf(x) - 1.0f))

__device__ __forceinline__ void lds_fence() {
    asm volatile("s_waitcnt lgkmcnt(0)" ::: "memory");
}

typedef __attribute__((ext_vector_type(8))) short short8v;
typedef __attribute__((ext_vector_type(4))) float f32x4;
#define MFMA32(a, b, c) __builtin_amdgcn_mfma_f32_16x16x32_bf16(a, b, c, 0, 0, 0)

__device__ __forceinline__ short f2bf(float x) {
    __hip_bfloat16 h = __float2bfloat16(x);
    return *reinterpret_cast<short*>(&h);
}
__device__ __forceinline__ float bf2f(short x) {
    unsigned u = ((unsigned)(unsigned short)x) << 16;
    return __uint_as_float(u);
}
__device__ __forceinline__ void gload_lds16(const float* g, float* l) {
    __builtin_amdgcn_global_load_lds(
        (const __attribute__((address_space(1))) void*)g,
        (__attribute__((address_space(3))) void*)l,
        16, 0, 0);
}

// ---------------- Kernel 1: X-transform via MFMA (unchanged) ----------------
#define XW_WC   0        // bf16 frag entries: idx=(part*16+u)*64+lane, 16B each (8192 words)
#define XW_WD1  8192     // wdep1: i*260 + j*16 + k  (4160 words)
#define XW_WD2  12352    // wdep2 same               (4160)
#define XW_BC   16512    // bconv 256
#define XW_BD1  16768    // 256
#define XW_BD2  17024    // 256
#define XW_SCR  17280    // + wave*4368 : per-point stride 273, scr[p*273 + j*17 + s]
#define XW_TOTAL (17280 + 4*4368)   // 34752 words = 139008 B

__global__ __launch_bounds__(256) void k_xform(
    const float* __restrict__ rep, const float* __restrict__ pts,
    const float* __restrict__ wconv, const float* __restrict__ bconv,
    const float* __restrict__ wdep1, const float* __restrict__ bdep1,
    const float* __restrict__ wdep2, const float* __restrict__ bdep2,
    float* __restrict__ x2)
{
    extern __shared__ __align__(16) float sm[];
    short* smh = (short*)sm;
    const int tid = threadIdx.x;

    for (int e = tid; e < 2048; e += 256) {
        const int part = e >> 10, u = (e >> 6) & 15, l = e & 63;
        const int g = l >> 4, s = l & 15;
        const int o = u * 16 + s;
        short8v v;
        if (part == 0) {
            #pragma unroll
            for (int t = 0; t < 8; ++t) v[t] = f2bf(wconv[o*48 + g*8 + t]);
        } else {
            #pragma unroll
            for (int t = 0; t < 4; ++t) v[t] = f2bf(wconv[o*48 + 32 + g*4 + t]);
            #pragma unroll
            for (int t = 4; t < 8; ++t) v[t] = 0;
        }
        *(short8v*)&smh[e * 8] = v;
    }
    for (int e = tid; e < 4096; e += 256) {
        const int i = e >> 8, j = (e >> 4) & 15, k = e & 15;
        sm[XW_WD1 + i*260 + j*16 + k] = wdep1[e];
        sm[XW_WD2 + i*260 + j*16 + k] = wdep2[e];
    }
    sm[XW_BC  + tid] = bconv[tid];
    sm[XW_BD1 + tid] = bdep1[tid];
    sm[XW_BD2 + tid] = bdep2[tid];
    __syncthreads();

    const int wave = tid >> 6, lane = tid & 63;
    const int g = lane >> 4, s = lane & 15;
    const int pt0 = (blockIdx.x * 4 + wave) * 16;

    const int p = pt0 + s;
    const float r0 = rep[p*3], r1 = rep[p*3+1], r2 = rep[p*3+2];
    short8v ah0, al0, ah1, al1;
    #pragma unroll
    for (int e = 0; e < 8; ++e) {
        const int r = g*8 + e;
        const int d = g >> 1, k = r & 15;
        const float v = pts[p*48 + k*3 + d] - (d == 0 ? r0 : r1);
        const short h = f2bf(v);
        ah0[e] = h; al0[e] = f2bf(v - bf2f(h));
    }
    #pragma unroll
    for (int e = 0; e < 4; ++e) {
        const int k = g*4 + e;
        const float v = pts[p*48 + k*3 + 2] - r2;
        const short h = f2bf(v);
        ah1[e] = h; al1[e] = f2bf(v - bf2f(h));
    }
    #pragma unroll
    for (int e = 4; e < 8; ++e) { ah1[e] = 0; al1[e] = 0; }

    f32x4 ex[16];
    #pragma unroll
    for (int u = 0; u < 16; ++u) {
        const float b = sm[XW_BC + u*16 + s];
        f32x4 acc; acc[0] = b; acc[1] = b; acc[2] = b; acc[3] = b;
        const short8v bh0 = *(const short8v*)&smh[(u*64 + lane) * 8];
        const short8v bh1 = *(const short8v*)&smh[((16 + u)*64 + lane) * 8];
        acc = MFMA32(ah0, bh0, acc);
        acc = MFMA32(ah1, bh1, acc);
        acc = MFMA32(al0, bh0, acc);
        acc = MFMA32(al1, bh1, acc);
        f32x4 r;
        r[0] = ELU(acc[0]); r[1] = ELU(acc[1]); r[2] = ELU(acc[2]); r[3] = ELU(acc[3]);
        ex[u] = r;
    }

    const int scrb = XW_SCR + wave * 4368;
    #pragma unroll
    for (int j = 0; j < 16; ++j) {
        const float b = sm[XW_BD1 + s*16 + j];
        f32x4 a; a[0] = b; a[1] = b; a[2] = b; a[3] = b;
        #pragma unroll
        for (int kb = 0; kb < 4; ++kb) {
            const float4 w = *(const float4*)&sm[XW_WD1 + s*260 + j*16 + kb*4];
            a += ex[kb*4+0] * w.x; a += ex[kb*4+1] * w.y;
            a += ex[kb*4+2] * w.z; a += ex[kb*4+3] * w.w;
        }
        #pragma unroll
        for (int q = 0; q < 4; ++q)
            sm[scrb + (g*4+q)*273 + j*17 + s] = ELU(a[q]);
    }
    lds_fence();

    f32x4 xr[16];
    #pragma unroll
    for (int k = 0; k < 16; ++k) {
        f32x4 v;
        #pragma unroll
        for (int q = 0; q < 4; ++q)
            v[q] = sm[scrb + (g*4+q)*273 + s*17 + k];
        xr[k] = v;
    }
    f32x4 oj[16];
    #pragma unroll
    for (int j = 0; j < 16; ++j) {
        const float b = sm[XW_BD2 + s*16 + j];
        f32x4 a; a[0] = b; a[1] = b; a[2] = b; a[3] = b;
        #pragma unroll
        for (int kb = 0; kb < 4; ++kb) {
            const float4 w = *(const float4*)&sm[XW_WD2 + s*260 + j*16 + kb*4];
            a += xr[kb*4+0] * w.x; a += xr[kb*4+1] * w.y;
            a += xr[kb*4+2] * w.z; a += xr[kb*4+3] * w.w;
        }
        oj[j] = a;
    }
    #pragma unroll
    for (int q = 0; q < 4; ++q) {
        const int pp = pt0 + g*4 + q;
        #pragma unroll
        for (int jb = 0; jb < 4; ++jb) {
            *(float4*)&x2[pp*256 + s*16 + jb*4] =
                make_float4(oj[jb*4+0][q], oj[jb*4+1][q], oj[jb*4+2][q], oj[jb*4+3][q]);
        }
    }
}

// ---------------- Kernel 2: MFMA features; dbuf global_load_lds + scalar prefetch ----------
// Grid 768 blocks (= 3 blocks/CU x 256, all resident; LDS 52.7KB/block) -> no tail.
// Each wave strides points by 3072 (10-11 pts, 97% balanced). Per iter: issue DMA(ptn) +
// scalar prefetch(ptn) -> phase A (implicit wait on scalars(pt) also retires DMA(pt), in-order
// vmcnt) -> vmcnt(8) safety -> phase B reads LDS.
#define NPTS 32768
#define TOTW 3072
__global__ __launch_bounds__(256, 3) void k_feat(
    const float* __restrict__ rep, const float* __restrict__ pts, const float* __restrict__ fts,
    const float* __restrict__ w1, const float* __restrict__ b1,
    const float* __restrict__ w2, const float* __restrict__ b2,
    const float* __restrict__ wdw, const float* __restrict__ bdw,
    float* __restrict__ xbuf)
{
    __shared__ __align__(16) short sw2[4096];      // B-frags: rec r=nt*2+h, 16B @ (r*64+lane)
    __shared__ __align__(16) uint2 sw1[64];        // j: {pack(w1[0][j],w1[1][j]), pack(w1[2][j],b1[j])}
    __shared__ __align__(16) unsigned swdwp[2560]; // [m][c] stride 10 (all-32-bank b64 reads)
    __shared__ float sbdw[256];
    __shared__ __align__(16) float sfts[4][2][1024]; // [wave][buf][fts point tile], 32KB
    const int tid = threadIdx.x;

    for (int idx = tid; idx < 512; idx += 256) {   // 512 recs of 8 bf16
        const int r = idx >> 6, l = idx & 63;
        const int nt = r >> 1, h = r & 1, gg = l >> 4, ss = l & 15;
        short8v v;
        #pragma unroll
        for (int e = 0; e < 8; ++e)
            v[e] = f2bf(w2[(h*32 + gg*8 + e)*64 + nt*16 + ss]);
        *(short8v*)&sw2[idx * 8] = v;
    }
    if (tid < 64) {
        const int j = tid;
        uint2 v;
        v.x = (unsigned)(unsigned short)f2bf(w1[j])
            | (((unsigned)(unsigned short)f2bf(w1[64 + j])) << 16);
        v.y = (unsigned)(unsigned short)f2bf(w1[128 + j])
            | (((unsigned)(unsigned short)f2bf(b1[j])) << 16);
        sw1[j] = v;
    }
    for (int e = tid; e < 2048; e += 256) {
        const int m = e >> 10, c = (e >> 3) & 127, w = e & 7;
        const unsigned lo = (unsigned)(unsigned short)f2bf(wdw[c*32 + m*16 + 2*w]);
        const unsigned hi = (unsigned)(unsigned short)f2bf(wdw[c*32 + m*16 + 2*w + 1]);
        swdwp[m*1280 + c*10 + w] = lo | (hi << 16);
    }
    sbdw[tid] = bdw[tid];
    __syncthreads();

    const int lane = tid & 63, wave = tid >> 6;
    const int g = lane >> 4, s = lane & 15;

    float b2c[4];
    #pragma unroll
    for (int nt = 0; nt < 4; ++nt) b2c[nt] = b2[nt*16 + s];

    const int gw = blockIdx.x * 4 + wave;   // 0..3071
    float* sf0 = &sfts[wave][0][0];
    float* sf1 = &sfts[wave][1][0];

    // ---- prologue: DMA pt=gw into buf0; prefetch scalars(gw) ----
    {
        const float* src = fts + (size_t)gw * 1024 + lane * 4;
        #pragma unroll
        for (int i = 0; i < 4; ++i) gload_lds16(src + i*256, sf0 + i*256);
    }
    float4 xv_n = *(const float4*)&xbuf[(size_t)gw*256 + s*16 + g*4];
    float p0_n = pts[gw*48 + s*3 + 0] - rep[gw*3 + 0];
    float p1_n = pts[gw*48 + s*3 + 1] - rep[gw*3 + 1];
    float p2_n = pts[gw*48 + s*3 + 2] - rep[gw*3 + 2];

    int k = 0;
    for (int pt = gw; pt < NPTS; pt += TOTW, ++k) {
        float* sfc = (k & 1) ? sf1 : sf0;
        float* sfn = (k & 1) ? sf0 : sf1;
        const int ptn = pt + TOTW;

        // consume prefetched scalars
        const float4 xv = xv_n;
        const float p0 = p0_n, p1 = p1_n, p2 = p2_n;

        // ---- issue DMA(ptn) + scalar prefetch(ptn) ----
        if (ptn < NPTS) {
            const float* src = fts + (size_t)ptn * 1024 + lane * 4;
            #pragma unroll
            for (int i = 0; i < 4; ++i) gload_lds16(src + i*256, sfn + i*256);
            xv_n = *(const float4*)&xbuf[(size_t)ptn*256 + s*16 + g*4];
            p0_n = pts[ptn*48 + s*3 + 0] - rep[ptn*3 + 0];
            p1_n = pts[ptn*48 + s*3 + 1] - rep[ptn*3 + 1];
            p2_n = pts[ptn*48 + s*3 + 2] - rep[ptn*3 + 2];
        }

        // ---- phase A: h1 (w1/b1 broadcast from LDS) in A-frag layout; h2 via 8 MFMA ----
        short8v af0, af1;
        #pragma unroll
        for (int t = 0; t < 2; ++t) {
            short8v f;
            #pragma unroll
            for (int e = 0; e < 8; ++e) {
                const uint2 pk = sw1[t*32 + g*8 + e];
                const float wx = __uint_as_float(pk.x << 16);
                const float wy = __uint_as_float(pk.x & 0xffff0000u);
                const float wz = __uint_as_float(pk.y << 16);
                const float bb = __uint_as_float(pk.y & 0xffff0000u);
                float h = bb + p0*wx + p1*wy + p2*wz;
                h = ELU(h);
                f[e] = f2bf(h);
            }
            if (t == 0) af0 = f; else af1 = f;
        }
        f32x4 hacc[4];
        #pragma unroll
        for (int nt = 0; nt < 4; ++nt) {
            f32x4 a; a[0] = b2c[nt]; a[1] = b2c[nt]; a[2] = b2c[nt]; a[3] = b2c[nt];
            const short8v bf0 = *(const short8v*)&sw2[((nt*2 + 0)*64 + lane) * 8];
            const short8v bf1 = *(const short8v*)&sw2[((nt*2 + 1)*64 + lane) * 8];
            a = MFMA32(af0, bf0, a);
            a = MFMA32(af1, bf1, a);
            hacc[nt] = a;
        }
        short8v a2 = (short8v)0;
        a2[0] = f2bf(xv.x); a2[1] = f2bf(xv.y);
        a2[2] = f2bf(xv.z); a2[3] = f2bf(xv.w);

        // ---- ensure DMA(pt) retired (it is >=12 deep by now; steady-state no stall) ----
        if (ptn < NPTS) { asm volatile("s_waitcnt vmcnt(8)" ::: "memory"); }
        else           { asm volatile("s_waitcnt vmcnt(0)" ::: "memory"); }

        // ---- phase B+C fused per 16-col tile u ----
        #pragma unroll
        for (int u = 0; u < 8; ++u) {
            short8v bfrag = (short8v)0;
            if (u < 4) {
                #pragma unroll
                for (int q = 0; q < 4; ++q) bfrag[q] = f2bf(ELU(hacc[u][q]));
            } else {
                #pragma unroll
                for (int e = 0; e < 4; ++e)
                    bfrag[e] = f2bf(sfc[(g*4 + e)*64 + (u - 4)*16 + s]);
            }
            f32x4 z; z[0] = 0.f; z[1] = 0.f; z[2] = 0.f; z[3] = 0.f;
            const f32x4 fx = MFMA32(a2, bfrag, z);   // fts_X[4g+q][u*16+s]

            const int c = u*16 + s;
            const int wo = c*10 + 2*g;               // stride-10: banks (10s+2g)%32, all 32 used
            const uint2 wm0 = *(const uint2*)&swdwp[wo];
            const uint2 wm1 = *(const uint2*)&swdwp[1280 + wo];
            const float a0 = __uint_as_float(wm0.x << 16);
            const float a1 = __uint_as_float(wm0.x & 0xffff0000u);
            const float a2f = __uint_as_float(wm0.y << 16);
            const float a3 = __uint_as_float(wm0.y & 0xffff0000u);
            const float c0 = __uint_as_float(wm1.x << 16);
            const float c1 = __uint_as_float(wm1.x & 0xffff0000u);
            const float c2 = __uint_as_float(wm1.y << 16);
            const float c3 = __uint_as_float(wm1.y & 0xffff0000u);
            float q0 = fx[0]*a0 + fx[1]*a1 + fx[2]*a2f + fx[3]*a3;
            float q1 = fx[0]*c0 + fx[1]*c1 + fx[2]*c2 + fx[3]*c3;
            q0 += __shfl_xor(q0, 16); q0 += __shfl_xor(q0, 32);
            q1 += __shfl_xor(q1, 16); q1 += __shfl_xor(q1, 32);
            if (lane < 16) {
                float2 r; r.x = q0 + sbdw[2*c]; r.y = q1 + sbdw[2*c + 1];
                *(float2*)&xbuf[(size_t)pt*256 + 2*c] = r;
            }
        }
    }
}

// ---------------- Kernel 3: out = elu(tmp @ wpw^T + bpw) via MFMA (unchanged) ----------------
__global__ __launch_bounds__(256) void k_out(
    const float* __restrict__ tmp, const float* __restrict__ wpw,
    const float* __restrict__ bpw, float* __restrict__ out)
{
    __shared__ unsigned sb[16384];   // 64KB: [n][chunk cb^(n&7)][wi]
    const int tid = threadIdx.x;
    for (int e = tid; e < 16384; e += 256) {
        const int n = e >> 7, kw = e & 127;
        const int cb = kw >> 2, wi = kw & 3;
        const unsigned lo = (unsigned)(unsigned short)f2bf(wpw[n*256 + 2*kw]);
        const unsigned hi = (unsigned)(unsigned short)f2bf(wpw[n*256 + 2*kw + 1]);
        sb[n*128 + ((cb ^ (n & 7)) << 2) + wi] = lo | (hi << 16);
    }
    __syncthreads();

    const int lane = tid & 63, wave = tid >> 6;
    const int g = lane >> 4, s = lane & 15;
    const int row = blockIdx.x * 64 + wave * 16 + s;

    f32x4 acc[8];
    #pragma unroll
    for (int nt = 0; nt < 8; ++nt) {
        const float b = bpw[nt*16 + s];
        acc[nt][0] = b; acc[nt][1] = b; acc[nt][2] = b; acc[nt][3] = b;
    }

    const float* arow = tmp + (size_t)row * 256 + g*8;
    float4 pa0 = *(const float4*)(arow);
    float4 pa1 = *(const float4*)(arow + 4);

    #pragma unroll
    for (int kk = 0; kk < 8; ++kk) {
        const float4 a0 = pa0, a1 = pa1;
        if (kk < 7) {
            pa0 = *(const float4*)(arow + (kk+1)*32);
            pa1 = *(const float4*)(arow + (kk+1)*32 + 4);
        }
        short8v ah, al;
        const float av[8] = {a0.x, a0.y, a0.z, a0.w, a1.x, a1.y, a1.z, a1.w};
        #pragma unroll
        for (int e = 0; e < 8; ++e) {
            const short h = f2bf(av[e]);
            ah[e] = h;
            al[e] = f2bf(av[e] - bf2f(h));
        }
        #pragma unroll
        for (int nt = 0; nt < 8; ++nt) {
            const short8v bf = *(const short8v*)&sb[(nt*16 + s)*128 + (((kk*4 + g) ^ (s & 7)) << 2)];
            acc[nt] = MFMA32(ah, bf, acc[nt]);
            acc[nt] = MFMA32(al, bf, acc[nt]);
        }
    }
    const int rbase = blockIdx.x * 64 + wave * 16 + 4*g;
    #pragma unroll
    for (int nt = 0; nt < 8; ++nt)
        #pragma unroll
        for (int q = 0; q < 4; ++q)
            out[(size_t)(rbase + q) * 128 + nt*16 + s] = ELU(acc[nt][q]);
}

extern "C" void kernel_launch(void* const* d_in, const int* in_sizes, int n_in,
                              void* d_out, int out_size, void* d_ws, size_t ws_size,
                              hipStream_t stream)
{
    (void)in_sizes; (void)n_in; (void)out_size; (void)ws_size;
    const float* rep   = (const float*)d_in[0];
    const float* pts   = (const float*)d_in[1];
    const float* fts   = (const float*)d_in[2];
    const float* w1    = (const float*)d_in[3];
    const float* b1    = (const float*)d_in[4];
    const float* w2    = (const float*)d_in[5];
    const float* b2    = (const float*)d_in[6];
    const float* wconv = (const float*)d_in[7];
    const float* bconv = (const float*)d_in[8];
    const float* wdep1 = (const float*)d_in[9];
    const float* bdep1 = (const float*)d_in[10];
    const float* wdep2 = (const float*)d_in[11];
    const float* bdep2 = (const float*)d_in[12];
    const float* wdw   = (const float*)d_in[13];
    const float* bdw   = (const float*)d_in[14];
    const float* wpw   = (const float*)d_in[15];
    const float* bpw   = (const float*)d_in[16];
    float* out  = (float*)d_out;
    float* xbuf = (float*)d_ws;   // 32768*256 floats = 33.5 MB

    hipFuncSetAttribute((const void*)k_xform, hipFuncAttributeMaxDynamicSharedMemorySize, XW_TOTAL*4);

    k_xform<<<dim3(512), dim3(256), XW_TOTAL*4, stream>>>(rep, pts, wconv, bconv, wdep1, bdep1, wdep2, bdep2, xbuf);
    k_feat <<<dim3(768), dim3(256), 0, stream>>>(rep, pts, fts, w1, b1, w2, b2, wdw, bdw, xbuf);
    k_out  <<<dim3(512), dim3(256), 0, stream>>>(xbuf, wpw, bpw, out);
}

// Round 12
// 103.507 us; speedup vs baseline: 2.8589x; 1.0187x over previous
//
#include <hip/hip_runtime.h>
#include <hip/hip_bf16.h>

// XConv: N=32 P=1024 K=16 DIMS=3 C_IN=64 C_MID=64 C_OUT=128 DM=2; NP=32768
// ws: 32768*256 floats (33.5 MB): holds X2 (untransposed), overwritten in-place by tmp.

#define ELU(x) ((x) > 0.0f ? (x) : (__expf(x) - 1.0f))

__device__ __forceinline__ void lds_fence() {
    asm volatile("s_waitcnt lgkmcnt(0)" ::: "memory");
}

typedef __attribute__((ext_vector_type(8))) short short8v;
typedef __attribute__((ext_vector_type(4))) float f32x4;
typedef __attribute__((ext_vector_type(2))) unsigned int uint2v;
#define MFMA32(a, b, c) __builtin_amdgcn_mfma_f32_16x16x32_bf16(a, b, c, 0, 0, 0)

__device__ __forceinline__ short f2bf(float x) {
    __hip_bfloat16 h = __float2bfloat16(x);
    return *reinterpret_cast<short*>(&h);
}
__device__ __forceinline__ float bf2f(short x) {
    unsigned u = ((unsigned)(unsigned short)x) << 16;
    return __uint_as_float(u);
}
__device__ __forceinline__ unsigned packbf(float a, float b) {
    return (unsigned)(unsigned short)f2bf(a) | (((unsigned)(unsigned short)f2bf(b)) << 16);
}
__device__ __forceinline__ void gload_lds16(const float* g, float* l) {
    __builtin_amdgcn_global_load_lds(
        (const __attribute__((address_space(1))) void*)g,
        (__attribute__((address_space(3))) void*)l,
        16, 0, 0);
}
// full xor-32 exchange+add, pure VALU: r.x/r.y hold both halves after swap
__device__ __forceinline__ float xor32_add(float q) {
    uint2v r = __builtin_amdgcn_permlane32_swap(__float_as_uint(q), __float_as_uint(q), false, false);
    return __uint_as_float(r.x) + __uint_as_float(r.y);
}

// ---------------- Kernel 1: X-transform via MFMA (unchanged) ----------------
#define XW_WC   0        // bf16 frag entries: idx=(part*16+u)*64+lane, 16B each (8192 words)
#define XW_WD1  8192     // wdep1: i*260 + j*16 + k  (4160 words)
#define XW_WD2  12352    // wdep2 same               (4160)
#define XW_BC   16512    // bconv 256
#define XW_BD1  16768    // 256
#define XW_BD2  17024    // 256
#define XW_SCR  17280    // + wave*4368 : per-point stride 273, scr[p*273 + j*17 + s]
#define XW_TOTAL (17280 + 4*4368)   // 34752 words = 139008 B

__global__ __launch_bounds__(256) void k_xform(
    const float* __restrict__ rep, const float* __restrict__ pts,
    const float* __restrict__ wconv, const float* __restrict__ bconv,
    const float* __restrict__ wdep1, const float* __restrict__ bdep1,
    const float* __restrict__ wdep2, const float* __restrict__ bdep2,
    float* __restrict__ x2)
{
    extern __shared__ __align__(16) float sm[];
    short* smh = (short*)sm;
    const int tid = threadIdx.x;

    for (int e = tid; e < 2048; e += 256) {
        const int part = e >> 10, u = (e >> 6) & 15, l = e & 63;
        const int g = l >> 4, s = l & 15;
        const int o = u * 16 + s;
        short8v v;
        if (part == 0) {
            #pragma unroll
            for (int t = 0; t < 8; ++t) v[t] = f2bf(wconv[o*48 + g*8 + t]);
        } else {
            #pragma unroll
            for (int t = 0; t < 4; ++t) v[t] = f2bf(wconv[o*48 + 32 + g*4 + t]);
            #pragma unroll
            for (int t = 4; t < 8; ++t) v[t] = 0;
        }
        *(short8v*)&smh[e * 8] = v;
    }
    for (int e = tid; e < 4096; e += 256) {
        const int i = e >> 8, j = (e >> 4) & 15, k = e & 15;
        sm[XW_WD1 + i*260 + j*16 + k] = wdep1[e];
        sm[XW_WD2 + i*260 + j*16 + k] = wdep2[e];
    }
    sm[XW_BC  + tid] = bconv[tid];
    sm[XW_BD1 + tid] = bdep1[tid];
    sm[XW_BD2 + tid] = bdep2[tid];
    __syncthreads();

    const int wave = tid >> 6, lane = tid & 63;
    const int g = lane >> 4, s = lane & 15;
    const int pt0 = (blockIdx.x * 4 + wave) * 16;

    const int p = pt0 + s;
    const float r0 = rep[p*3], r1 = rep[p*3+1], r2 = rep[p*3+2];
    short8v ah0, al0, ah1, al1;
    #pragma unroll
    for (int e = 0; e < 8; ++e) {
        const int r = g*8 + e;
        const int d = g >> 1, k = r & 15;
        const float v = pts[p*48 + k*3 + d] - (d == 0 ? r0 : r1);
        const short h = f2bf(v);
        ah0[e] = h; al0[e] = f2bf(v - bf2f(h));
    }
    #pragma unroll
    for (int e = 0; e < 4; ++e) {
        const int k = g*4 + e;
        const float v = pts[p*48 + k*3 + 2] - r2;
        const short h = f2bf(v);
        ah1[e] = h; al1[e] = f2bf(v - bf2f(h));
    }
    #pragma unroll
    for (int e = 4; e < 8; ++e) { ah1[e] = 0; al1[e] = 0; }

    f32x4 ex[16];
    #pragma unroll
    for (int u = 0; u < 16; ++u) {
        const float b = sm[XW_BC + u*16 + s];
        f32x4 acc; acc[0] = b; acc[1] = b; acc[2] = b; acc[3] = b;
        const short8v bh0 = *(const short8v*)&smh[(u*64 + lane) * 8];
        const short8v bh1 = *(const short8v*)&smh[((16 + u)*64 + lane) * 8];
        acc = MFMA32(ah0, bh0, acc);
        acc = MFMA32(ah1, bh1, acc);
        acc = MFMA32(al0, bh0, acc);
        acc = MFMA32(al1, bh1, acc);
        f32x4 r;
        r[0] = ELU(acc[0]); r[1] = ELU(acc[1]); r[2] = ELU(acc[2]); r[3] = ELU(acc[3]);
        ex[u] = r;
    }

    const int scrb = XW_SCR + wave * 4368;
    #pragma unroll
    for (int j = 0; j < 16; ++j) {
        const float b = sm[XW_BD1 + s*16 + j];
        f32x4 a; a[0] = b; a[1] = b; a[2] = b; a[3] = b;
        #pragma unroll
        for (int kb = 0; kb < 4; ++kb) {
            const float4 w = *(const float4*)&sm[XW_WD1 + s*260 + j*16 + kb*4];
            a += ex[kb*4+0] * w.x; a += ex[kb*4+1] * w.y;
            a += ex[kb*4+2] * w.z; a += ex[kb*4+3] * w.w;
        }
        #pragma unroll
        for (int q = 0; q < 4; ++q)
            sm[scrb + (g*4+q)*273 + j*17 + s] = ELU(a[q]);
    }
    lds_fence();

    f32x4 xr[16];
    #pragma unroll
    for (int k = 0; k < 16; ++k) {
        f32x4 v;
        #pragma unroll
        for (int q = 0; q < 4; ++q)
            v[q] = sm[scrb + (g*4+q)*273 + s*17 + k];
        xr[k] = v;
    }
    f32x4 oj[16];
    #pragma unroll
    for (int j = 0; j < 16; ++j) {
        const float b = sm[XW_BD2 + s*16 + j];
        f32x4 a; a[0] = b; a[1] = b; a[2] = b; a[3] = b;
        #pragma unroll
        for (int kb = 0; kb < 4; ++kb) {
            const float4 w = *(const float4*)&sm[XW_WD2 + s*260 + j*16 + kb*4];
            a += xr[kb*4+0] * w.x; a += xr[kb*4+1] * w.y;
            a += xr[kb*4+2] * w.z; a += xr[kb*4+3] * w.w;
        }
        oj[j] = a;
    }
    #pragma unroll
    for (int q = 0; q < 4; ++q) {
        const int pp = pt0 + g*4 + q;
        #pragma unroll
        for (int jb = 0; jb < 4; ++jb) {
            *(float4*)&x2[pp*256 + s*16 + jb*4] =
                make_float4(oj[jb*4+0][q], oj[jb*4+1][q], oj[jb*4+2][q], oj[jb*4+3][q]);
        }
    }
}

// ---------------- Kernel 2: MFMA features; dbuf DMA + reg wdw + batched reduce ----------
// Grid 768 (3 blocks/CU resident, no tail); LDS 41.7KB. Per iter: DMA(ptn)+scalar prefetch ->
// phase A -> vmcnt(8) -> phase B (all 8 MFMA+dot) -> batched shfl_xor(16) -> permlane32_swap
// (VALU) -> lane<16 stores. wdw held as 32 bf16-pair regs (static-indexed, loop-invariant).
#define NPTS 32768
#define TOTW 3072
__global__ __launch_bounds__(256, 3) void k_feat(
    const float* __restrict__ rep, const float* __restrict__ pts, const float* __restrict__ fts,
    const float* __restrict__ w1, const float* __restrict__ b1,
    const float* __restrict__ w2, const float* __restrict__ b2,
    const float* __restrict__ wdw, const float* __restrict__ bdw,
    float* __restrict__ xbuf)
{
    __shared__ __align__(16) short sw2[4096];      // B-frags: rec r=nt*2+h, 16B @ (r*64+lane)
    __shared__ __align__(16) uint2 sw1[64];        // j: {pack(w1[0][j],w1[1][j]), pack(w1[2][j],b1[j])}
    __shared__ float sbdw[256];
    __shared__ __align__(16) float sfts[4][2][1024]; // [wave][buf][fts point tile], 32KB
    const int tid = threadIdx.x;

    for (int idx = tid; idx < 512; idx += 256) {   // 512 recs of 8 bf16
        const int r = idx >> 6, l = idx & 63;
        const int nt = r >> 1, h = r & 1, gg = l >> 4, ss = l & 15;
        short8v v;
        #pragma unroll
        for (int e = 0; e < 8; ++e)
            v[e] = f2bf(w2[(h*32 + gg*8 + e)*64 + nt*16 + ss]);
        *(short8v*)&sw2[idx * 8] = v;
    }
    if (tid < 64) {
        const int j = tid;
        uint2 v;
        v.x = packbf(w1[j], w1[64 + j]);
        v.y = packbf(w1[128 + j], b1[j]);
        sw1[j] = v;
    }
    sbdw[tid] = bdw[tid];
    __syncthreads();

    const int lane = tid & 63, wave = tid >> 6;
    const int g = lane >> 4, s = lane & 15;

    float b2c[4];
    #pragma unroll
    for (int nt = 0; nt < 4; ++nt) b2c[nt] = b2[nt*16 + s];

    // ---- wdw -> per-lane regs (bf16 pairs), loop-invariant: wdw[c*32 + m*16 + k], k=4g+q ----
    uint2 wp0[8], wp1[8];
    #pragma unroll
    for (int u = 0; u < 8; ++u) {
        const int cb = (u*16 + s) * 32 + 4*g;
        wp0[u].x = packbf(wdw[cb + 0],  wdw[cb + 1]);
        wp0[u].y = packbf(wdw[cb + 2],  wdw[cb + 3]);
        wp1[u].x = packbf(wdw[cb + 16], wdw[cb + 17]);
        wp1[u].y = packbf(wdw[cb + 18], wdw[cb + 19]);
    }

    const int gw = blockIdx.x * 4 + wave;   // 0..3071
    float* sf0 = &sfts[wave][0][0];
    float* sf1 = &sfts[wave][1][0];

    // ---- prologue: DMA pt=gw into buf0; prefetch scalars(gw) ----
    {
        const float* src = fts + (size_t)gw * 1024 + lane * 4;
        #pragma unroll
        for (int i = 0; i < 4; ++i) gload_lds16(src + i*256, sf0 + i*256);
    }
    float4 xv_n = *(const float4*)&xbuf[(size_t)gw*256 + s*16 + g*4];
    float p0_n = pts[gw*48 + s*3 + 0] - rep[gw*3 + 0];
    float p1_n = pts[gw*48 + s*3 + 1] - rep[gw*3 + 1];
    float p2_n = pts[gw*48 + s*3 + 2] - rep[gw*3 + 2];

    int k = 0;
    for (int pt = gw; pt < NPTS; pt += TOTW, ++k) {
        float* sfc = (k & 1) ? sf1 : sf0;
        float* sfn = (k & 1) ? sf0 : sf1;
        const int ptn = pt + TOTW;

        const float4 xv = xv_n;
        const float p0 = p0_n, p1 = p1_n, p2 = p2_n;

        // ---- issue DMA(ptn) + scalar prefetch(ptn) ----
        if (ptn < NPTS) {
            const float* src = fts + (size_t)ptn * 1024 + lane * 4;
            #pragma unroll
            for (int i = 0; i < 4; ++i) gload_lds16(src + i*256, sfn + i*256);
            xv_n = *(const float4*)&xbuf[(size_t)ptn*256 + s*16 + g*4];
            p0_n = pts[ptn*48 + s*3 + 0] - rep[ptn*3 + 0];
            p1_n = pts[ptn*48 + s*3 + 1] - rep[ptn*3 + 1];
            p2_n = pts[ptn*48 + s*3 + 2] - rep[ptn*3 + 2];
        }

        // ---- phase A: h1 in A-frag layout; h2 via 8 MFMA ----
        short8v af0, af1;
        #pragma unroll
        for (int t = 0; t < 2; ++t) {
            short8v f;
            #pragma unroll
            for (int e = 0; e < 8; ++e) {
                const uint2 pk = sw1[t*32 + g*8 + e];
                const float wx = __uint_as_float(pk.x << 16);
                const float wy = __uint_as_float(pk.x & 0xffff0000u);
                const float wz = __uint_as_float(pk.y << 16);
                const float bb = __uint_as_float(pk.y & 0xffff0000u);
                float h = bb + p0*wx + p1*wy + p2*wz;
                h = ELU(h);
                f[e] = f2bf(h);
            }
            if (t == 0) af0 = f; else af1 = f;
        }
        f32x4 hacc[4];
        #pragma unroll
        for (int nt = 0; nt < 4; ++nt) {
            f32x4 a; a[0] = b2c[nt]; a[1] = b2c[nt]; a[2] = b2c[nt]; a[3] = b2c[nt];
            const short8v bf0 = *(const short8v*)&sw2[((nt*2 + 0)*64 + lane) * 8];
            const short8v bf1 = *(const short8v*)&sw2[((nt*2 + 1)*64 + lane) * 8];
            a = MFMA32(af0, bf0, a);
            a = MFMA32(af1, bf1, a);
            hacc[nt] = a;
        }
        short8v a2 = (short8v)0;
        a2[0] = f2bf(xv.x); a2[1] = f2bf(xv.y);
        a2[2] = f2bf(xv.z); a2[3] = f2bf(xv.w);

        // ---- ensure DMA(pt) retired (>=12 deep; steady-state no stall) ----
        if (ptn < NPTS) { asm volatile("s_waitcnt vmcnt(8)" ::: "memory"); }
        else           { asm volatile("s_waitcnt vmcnt(0)" ::: "memory"); }

        // ---- phase B: all 8 tiles -> q partials (reg wdw, no LDS) ----
        float q0a[8], q1a[8];
        #pragma unroll
        for (int u = 0; u < 8; ++u) {
            short8v bfrag = (short8v)0;
            if (u < 4) {
                #pragma unroll
                for (int q = 0; q < 4; ++q) bfrag[q] = f2bf(ELU(hacc[u][q]));
            } else {
                #pragma unroll
                for (int e = 0; e < 4; ++e)
                    bfrag[e] = f2bf(sfc[(g*4 + e)*64 + (u - 4)*16 + s]);
            }
            f32x4 z; z[0] = 0.f; z[1] = 0.f; z[2] = 0.f; z[3] = 0.f;
            const f32x4 fx = MFMA32(a2, bfrag, z);   // fts_X[4g+q][u*16+s]

            const float a0 = __uint_as_float(wp0[u].x << 16);
            const float a1 = __uint_as_float(wp0[u].x & 0xffff0000u);
            const float a2f = __uint_as_float(wp0[u].y << 16);
            const float a3 = __uint_as_float(wp0[u].y & 0xffff0000u);
            const float c0 = __uint_as_float(wp1[u].x << 16);
            const float c1 = __uint_as_float(wp1[u].x & 0xffff0000u);
            const float c2 = __uint_as_float(wp1[u].y << 16);
            const float c3 = __uint_as_float(wp1[u].y & 0xffff0000u);
            q0a[u] = fx[0]*a0 + fx[1]*a1 + fx[2]*a2f + fx[3]*a3;
            q1a[u] = fx[0]*c0 + fx[1]*c1 + fx[2]*c2 + fx[3]*c3;
        }
        // ---- batched xor-16 (16 independent ds_swizzles overlap) ----
        #pragma unroll
        for (int u = 0; u < 8; ++u) {
            q0a[u] += __shfl_xor(q0a[u], 16);
            q1a[u] += __shfl_xor(q1a[u], 16);
        }
        // ---- xor-32 via permlane32_swap (pure VALU) ----
        #pragma unroll
        for (int u = 0; u < 8; ++u) {
            q0a[u] = xor32_add(q0a[u]);
            q1a[u] = xor32_add(q1a[u]);
        }
        if (lane < 16) {   // g==0, s=lane
            #pragma unroll
            for (int u = 0; u < 8; ++u) {
                const int c = u*16 + s;
                float2 r; r.x = q0a[u] + sbdw[2*c]; r.y = q1a[u] + sbdw[2*c + 1];
                *(float2*)&xbuf[(size_t)pt*256 + 2*c] = r;
            }
        }
    }
}

// ---------------- Kernel 3: out = elu(tmp @ wpw^T + bpw) via MFMA (unchanged) ----------------
__global__ __launch_bounds__(256) void k_out(
    const float* __restrict__ tmp, const float* __restrict__ wpw,
    const float* __restrict__ bpw, float* __restrict__ out)
{
    __shared__ unsigned sb[16384];   // 64KB: [n][chunk cb^(n&7)][wi]
    const int tid = threadIdx.x;
    for (int e = tid; e < 16384; e += 256) {
        const int n = e >> 7, kw = e & 127;
        const int cb = kw >> 2, wi = kw & 3;
        const unsigned lo = (unsigned)(unsigned short)f2bf(wpw[n*256 + 2*kw]);
        const unsigned hi = (unsigned)(unsigned short)f2bf(wpw[n*256 + 2*kw + 1]);
        sb[n*128 + ((cb ^ (n & 7)) << 2) + wi] = lo | (hi << 16);
    }
    __syncthreads();

    const int lane = tid & 63, wave = tid >> 6;
    const int g = lane >> 4, s = lane & 15;
    const int row = blockIdx.x * 64 + wave * 16 + s;

    f32x4 acc[8];
    #pragma unroll
    for (int nt = 0; nt < 8; ++nt) {
        const float b = bpw[nt*16 + s];
        acc[nt][0] = b; acc[nt][1] = b; acc[nt][2] = b; acc[nt][3] = b;
    }

    const float* arow = tmp + (size_t)row * 256 + g*8;
    float4 pa0 = *(const float4*)(arow);
    float4 pa1 = *(const float4*)(arow + 4);

    #pragma unroll
    for (int kk = 0; kk < 8; ++kk) {
        const float4 a0 = pa0, a1 = pa1;
        if (kk < 7) {
            pa0 = *(const float4*)(arow + (kk+1)*32);
            pa1 = *(const float4*)(arow + (kk+1)*32 + 4);
        }
        short8v ah, al;
        const float av[8] = {a0.x, a0.y, a0.z, a0.w, a1.x, a1.y, a1.z, a1.w};
        #pragma unroll
        for (int e = 0; e < 8; ++e) {
            const short h = f2bf(av[e]);
            ah[e] = h;
            al[e] = f2bf(av[e] - bf2f(h));
        }
        #pragma unroll
        for (int nt = 0; nt < 8; ++nt) {
            const short8v bf = *(const short8v*)&sb[(nt*16 + s)*128 + (((kk*4 + g) ^ (s & 7)) << 2)];
            acc[nt] = MFMA32(ah, bf, acc[nt]);
            acc[nt] = MFMA32(al, bf, acc[nt]);
        }
    }
    const int rbase = blockIdx.x * 64 + wave * 16 + 4*g;
    #pragma unroll
    for (int nt = 0; nt < 8; ++nt)
        #pragma unroll
        for (int q = 0; q < 4; ++q)
            out[(size_t)(rbase + q) * 128 + nt*16 + s] = ELU(acc[nt][q]);
}

extern "C" void kernel_launch(void* const* d_in, const int* in_sizes, int n_in,
                              void* d_out, int out_size, void* d_ws, size_t ws_size,
                              hipStream_t stream)
{
    (void)in_sizes; (void)n_in; (void)out_size; (void)ws_size;
    const float* rep   = (const float*)d_in[0];
    const float* pts   = (const float*)d_in[1];
    const float* fts   = (const float*)d_in[2];
    const float* w1    = (const float*)d_in[3];
    const float* b1    = (const float*)d_in[4];
    const float* w2    = (const float*)d_in[5];
    const float* b2    = (const float*)d_in[6];
    const float* wconv = (const float*)d_in[7];
    const float* bconv = (const float*)d_in[8];
    const float* wdep1 = (const float*)d_in[9];
    const float* bdep1 = (const float*)d_in[10];
    const float* wdep2 = (const float*)d_in[11];
    const float* bdep2 = (const float*)d_in[12];
    const float* wdw   = (const float*)d_in[13];
    const float* bdw   = (const float*)d_in[14];
    const float* wpw   = (const float*)d_in[15];
    const float* bpw   = (const float*)d_in[16];
    float* out  = (float*)d_out;
    float* xbuf = (float*)d_ws;   // 32768*256 floats = 33.5 MB

    hipFuncSetAttribute((const void*)k_xform, hipFuncAttributeMaxDynamicSharedMemorySize, XW_TOTAL*4);

    k_xform<<<dim3(512), dim3(256), XW_TOTAL*4, stream>>>(rep, pts, wconv, bconv, wdep1, bdep1, wdep2, bdep2, xbuf);
    k_feat <<<dim3(768), dim3(256), 0, stream>>>(rep, pts, fts, w1, b1, w2, b2, wdw, bdw, xbuf);
    k_out  <<<dim3(512), dim3(256), 0, stream>>>(xbuf, wpw, bpw, out);
}

// Round 13
// 95.678 us; speedup vs baseline: 3.0928x; 1.0818x over previous
//
#include <hip/hip_runtime.h>
#include <hip/hip_bf16.h>

// XConv: N=32 P=1024 K=16 DIMS=3 C_IN=64 C_MID=64 C_OUT=128 DM=2; NP=32768
// ws layout: [0, 16.8MB) x2 as bf16 ; [32MB, 65.5MB) tmp fp32. No aliasing.

#define ELU(x) ((x) > 0.0f ? (x) : (__expf(x) - 1.0f))

__device__ __forceinline__ void lds_fence() {
    asm volatile("s_waitcnt lgkmcnt(0)" ::: "memory");
}

typedef __attribute__((ext_vector_type(8))) short short8v;
typedef __attribute__((ext_vector_type(4))) float f32x4;
typedef __attribute__((ext_vector_type(2))) unsigned int uint2v;
#define MFMA32(a, b, c) __builtin_amdgcn_mfma_f32_16x16x32_bf16(a, b, c, 0, 0, 0)

__device__ __forceinline__ short f2bf(float x) {
    __hip_bfloat16 h = __float2bfloat16(x);
    return *reinterpret_cast<short*>(&h);
}
__device__ __forceinline__ float bf2f(short x) {
    unsigned u = ((unsigned)(unsigned short)x) << 16;
    return __uint_as_float(u);
}
__device__ __forceinline__ unsigned packbf(float a, float b) {
    return (unsigned)(unsigned short)f2bf(a) | (((unsigned)(unsigned short)f2bf(b)) << 16);
}
__device__ __forceinline__ void gload_lds16(const float* g, float* l) {
    __builtin_amdgcn_global_load_lds(
        (const __attribute__((address_space(1))) void*)g,
        (__attribute__((address_space(3))) void*)l,
        16, 0, 0);
}
// full xor-32 exchange+add, pure VALU
__device__ __forceinline__ float xor32_add(float q) {
    uint2v r = __builtin_amdgcn_permlane32_swap(__float_as_uint(q), __float_as_uint(q), false, false);
    return __uint_as_float(r.x) + __uint_as_float(r.y);
}

// ---------------- Kernel 1: X-transform via MFMA (bf16 X2 output) ----------------
#define XW_WC   0        // bf16 frag entries: idx=(part*16+u)*64+lane, 16B each (8192 words)
#define XW_WD1  8192     // wdep1: i*260 + j*16 + k  (4160 words)
#define XW_WD2  12352    // wdep2 same               (4160)
#define XW_BC   16512    // bconv 256
#define XW_BD1  16768    // 256
#define XW_BD2  17024    // 256
#define XW_SCR  17280    // + wave*4368 : per-point stride 273, scr[p*273 + j*17 + s]
#define XW_TOTAL (17280 + 4*4368)   // 34752 words = 139008 B

__global__ __launch_bounds__(256) void k_xform(
    const float* __restrict__ rep, const float* __restrict__ pts,
    const float* __restrict__ wconv, const float* __restrict__ bconv,
    const float* __restrict__ wdep1, const float* __restrict__ bdep1,
    const float* __restrict__ wdep2, const float* __restrict__ bdep2,
    unsigned short* __restrict__ x2bf)
{
    extern __shared__ __align__(16) float sm[];
    short* smh = (short*)sm;
    const int tid = threadIdx.x;

    for (int e = tid; e < 2048; e += 256) {
        const int part = e >> 10, u = (e >> 6) & 15, l = e & 63;
        const int g = l >> 4, s = l & 15;
        const int o = u * 16 + s;
        short8v v;
        if (part == 0) {
            #pragma unroll
            for (int t = 0; t < 8; ++t) v[t] = f2bf(wconv[o*48 + g*8 + t]);
        } else {
            #pragma unroll
            for (int t = 0; t < 4; ++t) v[t] = f2bf(wconv[o*48 + 32 + g*4 + t]);
            #pragma unroll
            for (int t = 4; t < 8; ++t) v[t] = 0;
        }
        *(short8v*)&smh[e * 8] = v;
    }
    for (int e = tid; e < 4096; e += 256) {
        const int i = e >> 8, j = (e >> 4) & 15, k = e & 15;
        sm[XW_WD1 + i*260 + j*16 + k] = wdep1[e];
        sm[XW_WD2 + i*260 + j*16 + k] = wdep2[e];
    }
    sm[XW_BC  + tid] = bconv[tid];
    sm[XW_BD1 + tid] = bdep1[tid];
    sm[XW_BD2 + tid] = bdep2[tid];
    __syncthreads();

    const int wave = tid >> 6, lane = tid & 63;
    const int g = lane >> 4, s = lane & 15;
    const int pt0 = (blockIdx.x * 4 + wave) * 16;

    const int p = pt0 + s;
    const float r0 = rep[p*3], r1 = rep[p*3+1], r2 = rep[p*3+2];
    short8v ah0, al0, ah1, al1;
    #pragma unroll
    for (int e = 0; e < 8; ++e) {
        const int r = g*8 + e;
        const int d = g >> 1, k = r & 15;
        const float v = pts[p*48 + k*3 + d] - (d == 0 ? r0 : r1);
        const short h = f2bf(v);
        ah0[e] = h; al0[e] = f2bf(v - bf2f(h));
    }
    #pragma unroll
    for (int e = 0; e < 4; ++e) {
        const int k = g*4 + e;
        const float v = pts[p*48 + k*3 + 2] - r2;
        const short h = f2bf(v);
        ah1[e] = h; al1[e] = f2bf(v - bf2f(h));
    }
    #pragma unroll
    for (int e = 4; e < 8; ++e) { ah1[e] = 0; al1[e] = 0; }

    f32x4 ex[16];
    #pragma unroll
    for (int u = 0; u < 16; ++u) {
        const float b = sm[XW_BC + u*16 + s];
        f32x4 acc; acc[0] = b; acc[1] = b; acc[2] = b; acc[3] = b;
        const short8v bh0 = *(const short8v*)&smh[(u*64 + lane) * 8];
        const short8v bh1 = *(const short8v*)&smh[((16 + u)*64 + lane) * 8];
        acc = MFMA32(ah0, bh0, acc);
        acc = MFMA32(ah1, bh1, acc);
        acc = MFMA32(al0, bh0, acc);
        acc = MFMA32(al1, bh1, acc);
        f32x4 r;
        r[0] = ELU(acc[0]); r[1] = ELU(acc[1]); r[2] = ELU(acc[2]); r[3] = ELU(acc[3]);
        ex[u] = r;
    }

    const int scrb = XW_SCR + wave * 4368;
    #pragma unroll
    for (int j = 0; j < 16; ++j) {
        const float b = sm[XW_BD1 + s*16 + j];
        f32x4 a; a[0] = b; a[1] = b; a[2] = b; a[3] = b;
        #pragma unroll
        for (int kb = 0; kb < 4; ++kb) {
            const float4 w = *(const float4*)&sm[XW_WD1 + s*260 + j*16 + kb*4];
            a += ex[kb*4+0] * w.x; a += ex[kb*4+1] * w.y;
            a += ex[kb*4+2] * w.z; a += ex[kb*4+3] * w.w;
        }
        #pragma unroll
        for (int q = 0; q < 4; ++q)
            sm[scrb + (g*4+q)*273 + j*17 + s] = ELU(a[q]);
    }
    lds_fence();

    f32x4 xr[16];
    #pragma unroll
    for (int k = 0; k < 16; ++k) {
        f32x4 v;
        #pragma unroll
        for (int q = 0; q < 4; ++q)
            v[q] = sm[scrb + (g*4+q)*273 + s*17 + k];
        xr[k] = v;
    }
    f32x4 oj[16];
    #pragma unroll
    for (int j = 0; j < 16; ++j) {
        const float b = sm[XW_BD2 + s*16 + j];
        f32x4 a; a[0] = b; a[1] = b; a[2] = b; a[3] = b;
        #pragma unroll
        for (int kb = 0; kb < 4; ++kb) {
            const float4 w = *(const float4*)&sm[XW_WD2 + s*260 + j*16 + kb*4];
            a += xr[kb*4+0] * w.x; a += xr[kb*4+1] * w.y;
            a += xr[kb*4+2] * w.z; a += xr[kb*4+3] * w.w;
        }
        oj[j] = a;
    }
    // write X2 as bf16 (bit-identical to k_feat's former f2bf(xv))
    #pragma unroll
    for (int q = 0; q < 4; ++q) {
        const int pp = pt0 + g*4 + q;
        #pragma unroll
        for (int jb = 0; jb < 4; ++jb) {
            uint2 pk;
            pk.x = packbf(oj[jb*4+0][q], oj[jb*4+1][q]);
            pk.y = packbf(oj[jb*4+2][q], oj[jb*4+3][q]);
            *(uint2*)&x2bf[(size_t)pp*256 + s*16 + jb*4] = pk;
        }
    }
}

// ---------------- Kernel 2: MFMA features; corrected-pipeline DMA + reg wdw ----------
// Per iter: (1) issue DMA(ptn) -> (2) vmcnt(4): retires everything older (scalars(pt),
// DMA(pt) — both 1 iter old, already landed) while the 4 fresh DMAs stay in flight ->
// (3) scalar prefetch(ptn) -> phase A -> phase B (LDS reads safe per step 2).
// No fresh-load stall in steady state. x2 read as bf16 ushort4 (direct A-frag bits).
#define NPTS 32768
#define TOTW 3072
__global__ __launch_bounds__(256, 3) void k_feat(
    const float* __restrict__ rep, const float* __restrict__ pts, const float* __restrict__ fts,
    const float* __restrict__ w1, const float* __restrict__ b1,
    const float* __restrict__ w2, const float* __restrict__ b2,
    const float* __restrict__ wdw, const float* __restrict__ bdw,
    const unsigned short* __restrict__ x2bf, float* __restrict__ tmpb)
{
    __shared__ __align__(16) short sw2[4096];      // B-frags: rec r=nt*2+h, 16B @ (r*64+lane)
    __shared__ __align__(16) uint2 sw1[64];        // j: {pack(w1[0][j],w1[1][j]), pack(w1[2][j],b1[j])}
    __shared__ float sbdw[256];
    __shared__ __align__(16) float sfts[4][2][1024]; // [wave][buf][fts point tile], 32KB
    const int tid = threadIdx.x;

    for (int idx = tid; idx < 512; idx += 256) {   // 512 recs of 8 bf16
        const int r = idx >> 6, l = idx & 63;
        const int nt = r >> 1, h = r & 1, gg = l >> 4, ss = l & 15;
        short8v v;
        #pragma unroll
        for (int e = 0; e < 8; ++e)
            v[e] = f2bf(w2[(h*32 + gg*8 + e)*64 + nt*16 + ss]);
        *(short8v*)&sw2[idx * 8] = v;
    }
    if (tid < 64) {
        const int j = tid;
        uint2 v;
        v.x = packbf(w1[j], w1[64 + j]);
        v.y = packbf(w1[128 + j], b1[j]);
        sw1[j] = v;
    }
    sbdw[tid] = bdw[tid];
    __syncthreads();

    const int lane = tid & 63, wave = tid >> 6;
    const int g = lane >> 4, s = lane & 15;

    float b2c[4];
    #pragma unroll
    for (int nt = 0; nt < 4; ++nt) b2c[nt] = b2[nt*16 + s];

    // ---- wdw -> per-lane regs (bf16 pairs), loop-invariant ----
    uint2 wp0[8], wp1[8];
    #pragma unroll
    for (int u = 0; u < 8; ++u) {
        const int cb = (u*16 + s) * 32 + 4*g;
        wp0[u].x = packbf(wdw[cb + 0],  wdw[cb + 1]);
        wp0[u].y = packbf(wdw[cb + 2],  wdw[cb + 3]);
        wp1[u].x = packbf(wdw[cb + 16], wdw[cb + 17]);
        wp1[u].y = packbf(wdw[cb + 18], wdw[cb + 19]);
    }

    const int gw = blockIdx.x * 4 + wave;   // 0..3071
    float* sf0 = &sfts[wave][0][0];
    float* sf1 = &sfts[wave][1][0];

    // ---- prologue: DMA pt=gw into buf0; prefetch scalars(gw) ----
    {
        const float* src = fts + (size_t)gw * 1024 + lane * 4;
        #pragma unroll
        for (int i = 0; i < 4; ++i) gload_lds16(src + i*256, sf0 + i*256);
    }
    ushort4 xv_n = *(const ushort4*)&x2bf[(size_t)gw*256 + s*16 + g*4];
    float p0_n = pts[gw*48 + s*3 + 0] - rep[gw*3 + 0];
    float p1_n = pts[gw*48 + s*3 + 1] - rep[gw*3 + 1];
    float p2_n = pts[gw*48 + s*3 + 2] - rep[gw*3 + 2];

    int k = 0;
    for (int pt = gw; pt < NPTS; pt += TOTW, ++k) {
        float* sfc = (k & 1) ? sf1 : sf0;
        float* sfn = (k & 1) ? sf0 : sf1;
        const int ptn = pt + TOTW;

        // ---- step 1: issue DMA(ptn) ----
        if (ptn < NPTS) {
            const float* src = fts + (size_t)ptn * 1024 + lane * 4;
            #pragma unroll
            for (int i = 0; i < 4; ++i) gload_lds16(src + i*256, sfn + i*256);
        }
        // ---- step 2: retire everything older than the 4 fresh DMAs ----
        asm volatile("s_waitcnt vmcnt(4)" ::: "memory");

        // consume prefetched scalars (registers)
        const ushort4 xv = xv_n;
        const float p0 = p0_n, p1 = p1_n, p2 = p2_n;

        // ---- step 3: scalar prefetch(ptn) — in flight across this whole iter ----
        if (ptn < NPTS) {
            xv_n = *(const ushort4*)&x2bf[(size_t)ptn*256 + s*16 + g*4];
            p0_n = pts[ptn*48 + s*3 + 0] - rep[ptn*3 + 0];
            p1_n = pts[ptn*48 + s*3 + 1] - rep[ptn*3 + 1];
            p2_n = pts[ptn*48 + s*3 + 2] - rep[ptn*3 + 2];
        }

        // ---- phase A: h1 in A-frag layout; h2 via 8 MFMA ----
        short8v af0, af1;
        #pragma unroll
        for (int t = 0; t < 2; ++t) {
            short8v f;
            #pragma unroll
            for (int e = 0; e < 8; ++e) {
                const uint2 pk = sw1[t*32 + g*8 + e];
                const float wx = __uint_as_float(pk.x << 16);
                const float wy = __uint_as_float(pk.x & 0xffff0000u);
                const float wz = __uint_as_float(pk.y << 16);
                const float bb = __uint_as_float(pk.y & 0xffff0000u);
                float h = bb + p0*wx + p1*wy + p2*wz;
                h = ELU(h);
                f[e] = f2bf(h);
            }
            if (t == 0) af0 = f; else af1 = f;
        }
        f32x4 hacc[4];
        #pragma unroll
        for (int nt = 0; nt < 4; ++nt) {
            f32x4 a; a[0] = b2c[nt]; a[1] = b2c[nt]; a[2] = b2c[nt]; a[3] = b2c[nt];
            const short8v bf0 = *(const short8v*)&sw2[((nt*2 + 0)*64 + lane) * 8];
            const short8v bf1 = *(const short8v*)&sw2[((nt*2 + 1)*64 + lane) * 8];
            a = MFMA32(af0, bf0, a);
            a = MFMA32(af1, bf1, a);
            hacc[nt] = a;
        }
        short8v a2 = (short8v)0;
        a2[0] = (short)xv.x; a2[1] = (short)xv.y;
        a2[2] = (short)xv.z; a2[3] = (short)xv.w;

        // ---- phase B: all 8 tiles -> q partials (reg wdw, no LDS for weights) ----
        float q0a[8], q1a[8];
        #pragma unroll
        for (int u = 0; u < 8; ++u) {
            short8v bfrag = (short8v)0;
            if (u < 4) {
                #pragma unroll
                for (int q = 0; q < 4; ++q) bfrag[q] = f2bf(ELU(hacc[u][q]));
            } else {
                #pragma unroll
                for (int e = 0; e < 4; ++e)
                    bfrag[e] = f2bf(sfc[(g*4 + e)*64 + (u - 4)*16 + s]);
            }
            f32x4 z; z[0] = 0.f; z[1] = 0.f; z[2] = 0.f; z[3] = 0.f;
            const f32x4 fx = MFMA32(a2, bfrag, z);   // fts_X[4g+q][u*16+s]

            const float a0 = __uint_as_float(wp0[u].x << 16);
            const float a1 = __uint_as_float(wp0[u].x & 0xffff0000u);
            const float a2f = __uint_as_float(wp0[u].y << 16);
            const float a3 = __uint_as_float(wp0[u].y & 0xffff0000u);
            const float c0 = __uint_as_float(wp1[u].x << 16);
            const float c1 = __uint_as_float(wp1[u].x & 0xffff0000u);
            const float c2 = __uint_as_float(wp1[u].y << 16);
            const float c3 = __uint_as_float(wp1[u].y & 0xffff0000u);
            q0a[u] = fx[0]*a0 + fx[1]*a1 + fx[2]*a2f + fx[3]*a3;
            q1a[u] = fx[0]*c0 + fx[1]*c1 + fx[2]*c2 + fx[3]*c3;
        }
        // ---- batched xor-16 (independent ds_swizzles overlap) ----
        #pragma unroll
        for (int u = 0; u < 8; ++u) {
            q0a[u] += __shfl_xor(q0a[u], 16);
            q1a[u] += __shfl_xor(q1a[u], 16);
        }
        // ---- xor-32 via permlane32_swap (pure VALU) ----
        #pragma unroll
        for (int u = 0; u < 8; ++u) {
            q0a[u] = xor32_add(q0a[u]);
            q1a[u] = xor32_add(q1a[u]);
        }
        if (lane < 16) {   // g==0, s=lane
            #pragma unroll
            for (int u = 0; u < 8; ++u) {
                const int c = u*16 + s;
                float2 r; r.x = q0a[u] + sbdw[2*c]; r.y = q1a[u] + sbdw[2*c + 1];
                *(float2*)&tmpb[(size_t)pt*256 + 2*c] = r;
            }
        }
    }
}

// ---------------- Kernel 3: out = elu(tmp @ wpw^T + bpw) via MFMA (unchanged) ----------------
__global__ __launch_bounds__(256) void k_out(
    const float* __restrict__ tmp, const float* __restrict__ wpw,
    const float* __restrict__ bpw, float* __restrict__ out)
{
    __shared__ unsigned sb[16384];   // 64KB: [n][chunk cb^(n&7)][wi]
    const int tid = threadIdx.x;
    for (int e = tid; e < 16384; e += 256) {
        const int n = e >> 7, kw = e & 127;
        const int cb = kw >> 2, wi = kw & 3;
        const unsigned lo = (unsigned)(unsigned short)f2bf(wpw[n*256 + 2*kw]);
        const unsigned hi = (unsigned)(unsigned short)f2bf(wpw[n*256 + 2*kw + 1]);
        sb[n*128 + ((cb ^ (n & 7)) << 2) + wi] = lo | (hi << 16);
    }
    __syncthreads();

    const int lane = tid & 63, wave = tid >> 6;
    const int g = lane >> 4, s = lane & 15;
    const int row = blockIdx.x * 64 + wave * 16 + s;

    f32x4 acc[8];
    #pragma unroll
    for (int nt = 0; nt < 8; ++nt) {
        const float b = bpw[nt*16 + s];
        acc[nt][0] = b; acc[nt][1] = b; acc[nt][2] = b; acc[nt][3] = b;
    }

    const float* arow = tmp + (size_t)row * 256 + g*8;
    float4 pa0 = *(const float4*)(arow);
    float4 pa1 = *(const float4*)(arow + 4);

    #pragma unroll
    for (int kk = 0; kk < 8; ++kk) {
        const float4 a0 = pa0, a1 = pa1;
        if (kk < 7) {
            pa0 = *(const float4*)(arow + (kk+1)*32);
            pa1 = *(const float4*)(arow + (kk+1)*32 + 4);
        }
        short8v ah, al;
        const float av[8] = {a0.x, a0.y, a0.z, a0.w, a1.x, a1.y, a1.z, a1.w};
        #pragma unroll
        for (int e = 0; e < 8; ++e) {
            const short h = f2bf(av[e]);
            ah[e] = h;
            al[e] = f2bf(av[e] - bf2f(h));
        }
        #pragma unroll
        for (int nt = 0; nt < 8; ++nt) {
            const short8v bf = *(const short8v*)&sb[(nt*16 + s)*128 + (((kk*4 + g) ^ (s & 7)) << 2)];
            acc[nt] = MFMA32(ah, bf, acc[nt]);
            acc[nt] = MFMA32(al, bf, acc[nt]);
        }
    }
    const int rbase = blockIdx.x * 64 + wave * 16 + 4*g;
    #pragma unroll
    for (int nt = 0; nt < 8; ++nt)
        #pragma unroll
        for (int q = 0; q < 4; ++q)
            out[(size_t)(rbase + q) * 128 + nt*16 + s] = ELU(acc[nt][q]);
}

extern "C" void kernel_launch(void* const* d_in, const int* in_sizes, int n_in,
                              void* d_out, int out_size, void* d_ws, size_t ws_size,
                              hipStream_t stream)
{
    (void)in_sizes; (void)n_in; (void)out_size; (void)ws_size;
    const float* rep   = (const float*)d_in[0];
    const float* pts   = (const float*)d_in[1];
    const float* fts   = (const float*)d_in[2];
    const float* w1    = (const float*)d_in[3];
    const float* b1    = (const float*)d_in[4];
    const float* w2    = (const float*)d_in[5];
    const float* b2    = (const float*)d_in[6];
    const float* wconv = (const float*)d_in[7];
    const float* bconv = (const float*)d_in[8];
    const float* wdep1 = (const float*)d_in[9];
    const float* bdep1 = (const float*)d_in[10];
    const float* wdep2 = (const float*)d_in[11];
    const float* bdep2 = (const float*)d_in[12];
    const float* wdw   = (const float*)d_in[13];
    const float* bdw   = (const float*)d_in[14];
    const float* wpw   = (const float*)d_in[15];
    const float* bpw   = (const float*)d_in[16];
    float* out  = (float*)d_out;
    unsigned short* x2bf = (unsigned short*)d_ws;                       // 16.8 MB
    float* tmpb = (float*)((char*)d_ws + (size_t)32 * 1024 * 1024);     // 33.5 MB

    hipFuncSetAttribute((const void*)k_xform, hipFuncAttributeMaxDynamicSharedMemorySize, XW_TOTAL*4);

    k_xform<<<dim3(512), dim3(256), XW_TOTAL*4, stream>>>(rep, pts, wconv, bconv, wdep1, bdep1, wdep2, bdep2, x2bf);
    k_feat <<<dim3(768), dim3(256), 0, stream>>>(rep, pts, fts, w1, b1, w2, b2, wdw, bdw, x2bf, tmpb);
    k_out  <<<dim3(512), dim3(256), 0, stream>>>(tmpb, wpw, bpw, out);
}

// Round 14
// 93.901 us; speedup vs baseline: 3.1513x; 1.0189x over previous
//
#include <hip/hip_runtime.h>
#include <hip/hip_bf16.h>

// XConv: N=32 P=1024 K=16 DIMS=3 C_IN=64 C_MID=64 C_OUT=128 DM=2; NP=32768
// ws layout: [0, 16.8MB) x2 bf16 ; [32MB, 48.8MB) tmp bf16. No aliasing.

#define ELU(x) ((x) > 0.0f ? (x) : (__expf(x) - 1.0f))

__device__ __forceinline__ void lds_fence() {
    asm volatile("s_waitcnt lgkmcnt(0)" ::: "memory");
}

typedef __attribute__((ext_vector_type(8))) short short8v;
typedef __attribute__((ext_vector_type(4))) float f32x4;
typedef __attribute__((ext_vector_type(2))) unsigned int uint2v;
#define MFMA32(a, b, c) __builtin_amdgcn_mfma_f32_16x16x32_bf16(a, b, c, 0, 0, 0)

__device__ __forceinline__ short f2bf(float x) {
    __hip_bfloat16 h = __float2bfloat16(x);
    return *reinterpret_cast<short*>(&h);
}
__device__ __forceinline__ float bf2f(short x) {
    unsigned u = ((unsigned)(unsigned short)x) << 16;
    return __uint_as_float(u);
}
__device__ __forceinline__ unsigned packbf(float a, float b) {
    return (unsigned)(unsigned short)f2bf(a) | (((unsigned)(unsigned short)f2bf(b)) << 16);
}
__device__ __forceinline__ void gload_lds16(const float* g, float* l) {
    __builtin_amdgcn_global_load_lds(
        (const __attribute__((address_space(1))) void*)g,
        (__attribute__((address_space(3))) void*)l,
        16, 0, 0);
}
// full xor-32 exchange+add, pure VALU
__device__ __forceinline__ float xor32_add(float q) {
    uint2v r = __builtin_amdgcn_permlane32_swap(__float_as_uint(q), __float_as_uint(q), false, false);
    return __uint_as_float(r.x) + __uint_as_float(r.y);
}

// ---------------- Kernel 1: X-transform via MFMA (bf16 X2 output) ----------------
#define XW_WC   0        // bf16 frag entries: idx=(part*16+u)*64+lane, 16B each (8192 words)
#define XW_WD1  8192     // wdep1: i*260 + j*16 + k  (4160 words)
#define XW_WD2  12352    // wdep2 same               (4160)
#define XW_BC   16512    // bconv 256
#define XW_BD1  16768    // 256
#define XW_BD2  17024    // 256
#define XW_SCR  17280    // + wave*4368 : per-point stride 273, scr[p*273 + j*17 + s]
#define XW_TOTAL (17280 + 4*4368)   // 34752 words = 139008 B

__global__ __launch_bounds__(256) void k_xform(
    const float* __restrict__ rep, const float* __restrict__ pts,
    const float* __restrict__ wconv, const float* __restrict__ bconv,
    const float* __restrict__ wdep1, const float* __restrict__ bdep1,
    const float* __restrict__ wdep2, const float* __restrict__ bdep2,
    unsigned short* __restrict__ x2bf)
{
    extern __shared__ __align__(16) float sm[];
    short* smh = (short*)sm;
    const int tid = threadIdx.x;

    for (int e = tid; e < 2048; e += 256) {
        const int part = e >> 10, u = (e >> 6) & 15, l = e & 63;
        const int g = l >> 4, s = l & 15;
        const int o = u * 16 + s;
        short8v v;
        if (part == 0) {
            #pragma unroll
            for (int t = 0; t < 8; ++t) v[t] = f2bf(wconv[o*48 + g*8 + t]);
        } else {
            #pragma unroll
            for (int t = 0; t < 4; ++t) v[t] = f2bf(wconv[o*48 + 32 + g*4 + t]);
            #pragma unroll
            for (int t = 4; t < 8; ++t) v[t] = 0;
        }
        *(short8v*)&smh[e * 8] = v;
    }
    for (int e = tid; e < 4096; e += 256) {
        const int i = e >> 8, j = (e >> 4) & 15, k = e & 15;
        sm[XW_WD1 + i*260 + j*16 + k] = wdep1[e];
        sm[XW_WD2 + i*260 + j*16 + k] = wdep2[e];
    }
    sm[XW_BC  + tid] = bconv[tid];
    sm[XW_BD1 + tid] = bdep1[tid];
    sm[XW_BD2 + tid] = bdep2[tid];
    __syncthreads();

    const int wave = tid >> 6, lane = tid & 63;
    const int g = lane >> 4, s = lane & 15;
    const int pt0 = (blockIdx.x * 4 + wave) * 16;

    const int p = pt0 + s;
    const float r0 = rep[p*3], r1 = rep[p*3+1], r2 = rep[p*3+2];
    short8v ah0, al0, ah1, al1;
    #pragma unroll
    for (int e = 0; e < 8; ++e) {
        const int r = g*8 + e;
        const int d = g >> 1, k = r & 15;
        const float v = pts[p*48 + k*3 + d] - (d == 0 ? r0 : r1);
        const short h = f2bf(v);
        ah0[e] = h; al0[e] = f2bf(v - bf2f(h));
    }
    #pragma unroll
    for (int e = 0; e < 4; ++e) {
        const int k = g*4 + e;
        const float v = pts[p*48 + k*3 + 2] - r2;
        const short h = f2bf(v);
        ah1[e] = h; al1[e] = f2bf(v - bf2f(h));
    }
    #pragma unroll
    for (int e = 4; e < 8; ++e) { ah1[e] = 0; al1[e] = 0; }

    f32x4 ex[16];
    #pragma unroll
    for (int u = 0; u < 16; ++u) {
        const float b = sm[XW_BC + u*16 + s];
        f32x4 acc; acc[0] = b; acc[1] = b; acc[2] = b; acc[3] = b;
        const short8v bh0 = *(const short8v*)&smh[(u*64 + lane) * 8];
        const short8v bh1 = *(const short8v*)&smh[((16 + u)*64 + lane) * 8];
        acc = MFMA32(ah0, bh0, acc);
        acc = MFMA32(ah1, bh1, acc);
        acc = MFMA32(al0, bh0, acc);
        acc = MFMA32(al1, bh1, acc);
        f32x4 r;
        r[0] = ELU(acc[0]); r[1] = ELU(acc[1]); r[2] = ELU(acc[2]); r[3] = ELU(acc[3]);
        ex[u] = r;
    }

    const int scrb = XW_SCR + wave * 4368;
    #pragma unroll
    for (int j = 0; j < 16; ++j) {
        const float b = sm[XW_BD1 + s*16 + j];
        f32x4 a; a[0] = b; a[1] = b; a[2] = b; a[3] = b;
        #pragma unroll
        for (int kb = 0; kb < 4; ++kb) {
            const float4 w = *(const float4*)&sm[XW_WD1 + s*260 + j*16 + kb*4];
            a += ex[kb*4+0] * w.x; a += ex[kb*4+1] * w.y;
            a += ex[kb*4+2] * w.z; a += ex[kb*4+3] * w.w;
        }
        #pragma unroll
        for (int q = 0; q < 4; ++q)
            sm[scrb + (g*4+q)*273 + j*17 + s] = ELU(a[q]);
    }
    lds_fence();

    f32x4 xr[16];
    #pragma unroll
    for (int k = 0; k < 16; ++k) {
        f32x4 v;
        #pragma unroll
        for (int q = 0; q < 4; ++q)
            v[q] = sm[scrb + (g*4+q)*273 + s*17 + k];
        xr[k] = v;
    }
    f32x4 oj[16];
    #pragma unroll
    for (int j = 0; j < 16; ++j) {
        const float b = sm[XW_BD2 + s*16 + j];
        f32x4 a; a[0] = b; a[1] = b; a[2] = b; a[3] = b;
        #pragma unroll
        for (int kb = 0; kb < 4; ++kb) {
            const float4 w = *(const float4*)&sm[XW_WD2 + s*260 + j*16 + kb*4];
            a += xr[kb*4+0] * w.x; a += xr[kb*4+1] * w.y;
            a += xr[kb*4+2] * w.z; a += xr[kb*4+3] * w.w;
        }
        oj[j] = a;
    }
    #pragma unroll
    for (int q = 0; q < 4; ++q) {
        const int pp = pt0 + g*4 + q;
        #pragma unroll
        for (int jb = 0; jb < 4; ++jb) {
            uint2 pk;
            pk.x = packbf(oj[jb*4+0][q], oj[jb*4+1][q]);
            pk.y = packbf(oj[jb*4+2][q], oj[jb*4+3][q]);
            *(uint2*)&x2bf[(size_t)pp*256 + s*16 + jb*4] = pk;
        }
    }
}

// ---------------- Kernel 2: MFMA features; pipelined DMA; bf16 tmp output ----------
#define NPTS 32768
#define TOTW 3072
__global__ __launch_bounds__(256, 3) void k_feat(
    const float* __restrict__ rep, const float* __restrict__ pts, const float* __restrict__ fts,
    const float* __restrict__ w1, const float* __restrict__ b1,
    const float* __restrict__ w2, const float* __restrict__ b2,
    const float* __restrict__ wdw, const float* __restrict__ bdw,
    const unsigned short* __restrict__ x2bf, unsigned short* __restrict__ tmpbf)
{
    __shared__ __align__(16) short sw2[4096];      // B-frags: rec r=nt*2+h, 16B @ (r*64+lane)
    __shared__ __align__(16) uint2 sw1[64];        // j: {pack(w1[0][j],w1[1][j]), pack(w1[2][j],b1[j])}
    __shared__ float sbdw[256];
    __shared__ __align__(16) float sfts[4][2][1024]; // [wave][buf][fts point tile], 32KB
    const int tid = threadIdx.x;

    for (int idx = tid; idx < 512; idx += 256) {   // 512 recs of 8 bf16
        const int r = idx >> 6, l = idx & 63;
        const int nt = r >> 1, h = r & 1, gg = l >> 4, ss = l & 15;
        short8v v;
        #pragma unroll
        for (int e = 0; e < 8; ++e)
            v[e] = f2bf(w2[(h*32 + gg*8 + e)*64 + nt*16 + ss]);
        *(short8v*)&sw2[idx * 8] = v;
    }
    if (tid < 64) {
        const int j = tid;
        uint2 v;
        v.x = packbf(w1[j], w1[64 + j]);
        v.y = packbf(w1[128 + j], b1[j]);
        sw1[j] = v;
    }
    sbdw[tid] = bdw[tid];
    __syncthreads();

    const int lane = tid & 63, wave = tid >> 6;
    const int g = lane >> 4, s = lane & 15;

    float b2c[4];
    #pragma unroll
    for (int nt = 0; nt < 4; ++nt) b2c[nt] = b2[nt*16 + s];

    // ---- wdw -> per-lane regs (bf16 pairs), loop-invariant ----
    uint2 wp0[8], wp1[8];
    #pragma unroll
    for (int u = 0; u < 8; ++u) {
        const int cb = (u*16 + s) * 32 + 4*g;
        wp0[u].x = packbf(wdw[cb + 0],  wdw[cb + 1]);
        wp0[u].y = packbf(wdw[cb + 2],  wdw[cb + 3]);
        wp1[u].x = packbf(wdw[cb + 16], wdw[cb + 17]);
        wp1[u].y = packbf(wdw[cb + 18], wdw[cb + 19]);
    }

    const int gw = blockIdx.x * 4 + wave;   // 0..3071
    float* sf0 = &sfts[wave][0][0];
    float* sf1 = &sfts[wave][1][0];

    // ---- prologue: DMA pt=gw into buf0; prefetch scalars(gw) ----
    {
        const float* src = fts + (size_t)gw * 1024 + lane * 4;
        #pragma unroll
        for (int i = 0; i < 4; ++i) gload_lds16(src + i*256, sf0 + i*256);
    }
    ushort4 xv_n = *(const ushort4*)&x2bf[(size_t)gw*256 + s*16 + g*4];
    float p0_n = pts[gw*48 + s*3 + 0] - rep[gw*3 + 0];
    float p1_n = pts[gw*48 + s*3 + 1] - rep[gw*3 + 1];
    float p2_n = pts[gw*48 + s*3 + 2] - rep[gw*3 + 2];

    int k = 0;
    for (int pt = gw; pt < NPTS; pt += TOTW, ++k) {
        float* sfc = (k & 1) ? sf1 : sf0;
        float* sfn = (k & 1) ? sf0 : sf1;
        const int ptn = pt + TOTW;

        // ---- step 1: issue DMA(ptn) ----
        if (ptn < NPTS) {
            const float* src = fts + (size_t)ptn * 1024 + lane * 4;
            #pragma unroll
            for (int i = 0; i < 4; ++i) gload_lds16(src + i*256, sfn + i*256);
        }
        // ---- step 2: retire everything older than the 4 fresh DMAs ----
        asm volatile("s_waitcnt vmcnt(4)" ::: "memory");

        const ushort4 xv = xv_n;
        const float p0 = p0_n, p1 = p1_n, p2 = p2_n;

        // ---- step 3: scalar prefetch(ptn) ----
        if (ptn < NPTS) {
            xv_n = *(const ushort4*)&x2bf[(size_t)ptn*256 + s*16 + g*4];
            p0_n = pts[ptn*48 + s*3 + 0] - rep[ptn*3 + 0];
            p1_n = pts[ptn*48 + s*3 + 1] - rep[ptn*3 + 1];
            p2_n = pts[ptn*48 + s*3 + 2] - rep[ptn*3 + 2];
        }

        // ---- phase A: h1 in A-frag layout; h2 via 8 MFMA ----
        short8v af0, af1;
        #pragma unroll
        for (int t = 0; t < 2; ++t) {
            short8v f;
            #pragma unroll
            for (int e = 0; e < 8; ++e) {
                const uint2 pk = sw1[t*32 + g*8 + e];
                const float wx = __uint_as_float(pk.x << 16);
                const float wy = __uint_as_float(pk.x & 0xffff0000u);
                const float wz = __uint_as_float(pk.y << 16);
                const float bb = __uint_as_float(pk.y & 0xffff0000u);
                float h = bb + p0*wx + p1*wy + p2*wz;
                h = ELU(h);
                f[e] = f2bf(h);
            }
            if (t == 0) af0 = f; else af1 = f;
        }
        f32x4 hacc[4];
        #pragma unroll
        for (int nt = 0; nt < 4; ++nt) {
            f32x4 a; a[0] = b2c[nt]; a[1] = b2c[nt]; a[2] = b2c[nt]; a[3] = b2c[nt];
            const short8v bf0 = *(const short8v*)&sw2[((nt*2 + 0)*64 + lane) * 8];
            const short8v bf1 = *(const short8v*)&sw2[((nt*2 + 1)*64 + lane) * 8];
            a = MFMA32(af0, bf0, a);
            a = MFMA32(af1, bf1, a);
            hacc[nt] = a;
        }
        short8v a2 = (short8v)0;
        a2[0] = (short)xv.x; a2[1] = (short)xv.y;
        a2[2] = (short)xv.z; a2[3] = (short)xv.w;

        // ---- phase B: all 8 tiles -> q partials (reg wdw) ----
        float q0a[8], q1a[8];
        #pragma unroll
        for (int u = 0; u < 8; ++u) {
            short8v bfrag = (short8v)0;
            if (u < 4) {
                #pragma unroll
                for (int q = 0; q < 4; ++q) bfrag[q] = f2bf(ELU(hacc[u][q]));
            } else {
                #pragma unroll
                for (int e = 0; e < 4; ++e)
                    bfrag[e] = f2bf(sfc[(g*4 + e)*64 + (u - 4)*16 + s]);
            }
            f32x4 z; z[0] = 0.f; z[1] = 0.f; z[2] = 0.f; z[3] = 0.f;
            const f32x4 fx = MFMA32(a2, bfrag, z);   // fts_X[4g+q][u*16+s]

            const float a0 = __uint_as_float(wp0[u].x << 16);
            const float a1 = __uint_as_float(wp0[u].x & 0xffff0000u);
            const float a2f = __uint_as_float(wp0[u].y << 16);
            const float a3 = __uint_as_float(wp0[u].y & 0xffff0000u);
            const float c0 = __uint_as_float(wp1[u].x << 16);
            const float c1 = __uint_as_float(wp1[u].x & 0xffff0000u);
            const float c2 = __uint_as_float(wp1[u].y << 16);
            const float c3 = __uint_as_float(wp1[u].y & 0xffff0000u);
            q0a[u] = fx[0]*a0 + fx[1]*a1 + fx[2]*a2f + fx[3]*a3;
            q1a[u] = fx[0]*c0 + fx[1]*c1 + fx[2]*c2 + fx[3]*c3;
        }
        // ---- batched xor-16 ----
        #pragma unroll
        for (int u = 0; u < 8; ++u) {
            q0a[u] += __shfl_xor(q0a[u], 16);
            q1a[u] += __shfl_xor(q1a[u], 16);
        }
        // ---- xor-32 via permlane32_swap ----
        #pragma unroll
        for (int u = 0; u < 8; ++u) {
            q0a[u] = xor32_add(q0a[u]);
            q1a[u] = xor32_add(q1a[u]);
        }
        if (lane < 16) {   // g==0, s=lane
            #pragma unroll
            for (int u = 0; u < 8; ++u) {
                const int c = u*16 + s;
                const unsigned pk = packbf(q0a[u] + sbdw[2*c], q1a[u] + sbdw[2*c + 1]);
                *(unsigned*)&tmpbf[(size_t)pt*256 + 2*c] = pk;
            }
        }
    }
}

// ---------------- Kernel 3: out = elu(tmp_bf16 @ wpw^T + bpw) via MFMA ----------------
// tmp is bf16: a lane's 16B ushort8 at [row][kk*32+g*8] IS the MFMA A-fragment. 64 MFMA/wave.
__global__ __launch_bounds__(256) void k_out(
    const unsigned short* __restrict__ tmp, const float* __restrict__ wpw,
    const float* __restrict__ bpw, float* __restrict__ out)
{
    __shared__ unsigned sb[16384];   // 64KB: [n][chunk cb^(n&7)][wi]
    const int tid = threadIdx.x;
    for (int e = tid; e < 16384; e += 256) {
        const int n = e >> 7, kw = e & 127;
        const int cb = kw >> 2, wi = kw & 3;
        const unsigned lo = (unsigned)(unsigned short)f2bf(wpw[n*256 + 2*kw]);
        const unsigned hi = (unsigned)(unsigned short)f2bf(wpw[n*256 + 2*kw + 1]);
        sb[n*128 + ((cb ^ (n & 7)) << 2) + wi] = lo | (hi << 16);
    }
    __syncthreads();

    const int lane = tid & 63, wave = tid >> 6;
    const int g = lane >> 4, s = lane & 15;
    const int row = blockIdx.x * 64 + wave * 16 + s;

    f32x4 acc[8];
    #pragma unroll
    for (int nt = 0; nt < 8; ++nt) {
        const float b = bpw[nt*16 + s];
        acc[nt][0] = b; acc[nt][1] = b; acc[nt][2] = b; acc[nt][3] = b;
    }

    const unsigned short* arow = tmp + (size_t)row * 256 + g*8;
    short8v pa = *(const short8v*)(arow);

    #pragma unroll
    for (int kk = 0; kk < 8; ++kk) {
        const short8v a = pa;
        if (kk < 7) pa = *(const short8v*)(arow + (kk+1)*32);
        #pragma unroll
        for (int nt = 0; nt < 8; ++nt) {
            const short8v bf = *(const short8v*)&sb[(nt*16 + s)*128 + (((kk*4 + g) ^ (s & 7)) << 2)];
            acc[nt] = MFMA32(a, bf, acc[nt]);
        }
    }
    const int rbase = blockIdx.x * 64 + wave * 16 + 4*g;
    #pragma unroll
    for (int nt = 0; nt < 8; ++nt)
        #pragma unroll
        for (int q = 0; q < 4; ++q)
            out[(size_t)(rbase + q) * 128 + nt*16 + s] = ELU(acc[nt][q]);
}

extern "C" void kernel_launch(void* const* d_in, const int* in_sizes, int n_in,
                              void* d_out, int out_size, void* d_ws, size_t ws_size,
                              hipStream_t stream)
{
    (void)in_sizes; (void)n_in; (void)out_size; (void)ws_size;
    const float* rep   = (const float*)d_in[0];
    const float* pts   = (const float*)d_in[1];
    const float* fts   = (const float*)d_in[2];
    const float* w1    = (const float*)d_in[3];
    const float* b1    = (const float*)d_in[4];
    const float* w2    = (const float*)d_in[5];
    const float* b2    = (const float*)d_in[6];
    const float* wconv = (const float*)d_in[7];
    const float* bconv = (const float*)d_in[8];
    const float* wdep1 = (const float*)d_in[9];
    const float* bdep1 = (const float*)d_in[10];
    const float* wdep2 = (const float*)d_in[11];
    const float* bdep2 = (const float*)d_in[12];
    const float* wdw   = (const float*)d_in[13];
    const float* bdw   = (const float*)d_in[14];
    const float* wpw   = (const float*)d_in[15];
    const float* bpw   = (const float*)d_in[16];
    float* out  = (float*)d_out;
    unsigned short* x2bf  = (unsigned short*)d_ws;                       // 16.8 MB
    unsigned short* tmpbf = (unsigned short*)((char*)d_ws + (size_t)32 * 1024 * 1024); // 16.8 MB

    hipFuncSetAttribute((const void*)k_xform, hipFuncAttributeMaxDynamicSharedMemorySize, XW_TOTAL*4);

    k_xform<<<dim3(512), dim3(256), XW_TOTAL*4, stream>>>(rep, pts, wconv, bconv, wdep1, bdep1, wdep2, bdep2, x2bf);
    k_feat <<<dim3(768), dim3(256), 0, stream>>>(rep, pts, fts, w1, b1, w2, b2, wdw, bdw, x2bf, tmpbf);
    k_out  <<<dim3(512), dim3(256), 0, stream>>>(tmpbf, wpw, bpw, out);
}

// Round 15
// 93.787 us; speedup vs baseline: 3.1551x; 1.0012x over previous
//
#include <hip/hip_runtime.h>
#include <hip/hip_bf16.h>

// XConv: N=32 P=1024 K=16 DIMS=3 C_IN=64 C_MID=64 C_OUT=128 DM=2; NP=32768
// ws layout: [0, 16.8MB) x2 bf16 ; [32MB, 48.8MB) tmp bf16. No aliasing.

#define ELU(x) ((x) > 0.0f ? (x) : (__expf(x) - 1.0f))

__device__ __forceinline__ void lds_fence() {
    asm volatile("s_waitcnt lgkmcnt(0)" ::: "memory");
}

typedef __attribute__((ext_vector_type(8))) short short8v;
typedef __attribute__((ext_vector_type(4))) float f32x4;
typedef __attribute__((ext_vector_type(2))) unsigned int uint2v;
#define MFMA32(a, b, c) __builtin_amdgcn_mfma_f32_16x16x32_bf16(a, b, c, 0, 0, 0)

__device__ __forceinline__ short f2bf(float x) {
    __hip_bfloat16 h = __float2bfloat16(x);
    return *reinterpret_cast<short*>(&h);
}
__device__ __forceinline__ float bf2f(short x) {
    unsigned u = ((unsigned)(unsigned short)x) << 16;
    return __uint_as_float(u);
}
__device__ __forceinline__ unsigned packbf(float a, float b) {
    return (unsigned)(unsigned short)f2bf(a) | (((unsigned)(unsigned short)f2bf(b)) << 16);
}
__device__ __forceinline__ void gload_lds16(const float* g, float* l) {
    __builtin_amdgcn_global_load_lds(
        (const __attribute__((address_space(1))) void*)g,
        (__attribute__((address_space(3))) void*)l,
        16, 0, 0);
}
// full xor-32 exchange+add, pure VALU
__device__ __forceinline__ float xor32_add(float q) {
    uint2v r = __builtin_amdgcn_permlane32_swap(__float_as_uint(q), __float_as_uint(q), false, false);
    return __uint_as_float(r.x) + __uint_as_float(r.y);
}

// ---------------- Kernel 1: X-transform via MFMA (bf16 X2 output) ----------------
#define XW_WC   0        // bf16 frag entries: idx=(part*16+u)*64+lane, 16B each (8192 words)
#define XW_WD1  8192     // wdep1: i*260 + j*16 + k  (4160 words)
#define XW_WD2  12352    // wdep2 same               (4160)
#define XW_BC   16512    // bconv 256
#define XW_BD1  16768    // 256
#define XW_BD2  17024    // 256
#define XW_SCR  17280    // + wave*4368 : per-point stride 273, scr[p*273 + j*17 + s]
#define XW_TOTAL (17280 + 4*4368)   // 34752 words = 139008 B

__global__ __launch_bounds__(256) void k_xform(
    const float* __restrict__ rep, const float* __restrict__ pts,
    const float* __restrict__ wconv, const float* __restrict__ bconv,
    const float* __restrict__ wdep1, const float* __restrict__ bdep1,
    const float* __restrict__ wdep2, const float* __restrict__ bdep2,
    unsigned short* __restrict__ x2bf)
{
    extern __shared__ __align__(16) float sm[];
    short* smh = (short*)sm;
    const int tid = threadIdx.x;

    for (int e = tid; e < 2048; e += 256) {
        const int part = e >> 10, u = (e >> 6) & 15, l = e & 63;
        const int g = l >> 4, s = l & 15;
        const int o = u * 16 + s;
        short8v v;
        if (part == 0) {
            #pragma unroll
            for (int t = 0; t < 8; ++t) v[t] = f2bf(wconv[o*48 + g*8 + t]);
        } else {
            #pragma unroll
            for (int t = 0; t < 4; ++t) v[t] = f2bf(wconv[o*48 + 32 + g*4 + t]);
            #pragma unroll
            for (int t = 4; t < 8; ++t) v[t] = 0;
        }
        *(short8v*)&smh[e * 8] = v;
    }
    for (int e = tid; e < 4096; e += 256) {
        const int i = e >> 8, j = (e >> 4) & 15, k = e & 15;
        sm[XW_WD1 + i*260 + j*16 + k] = wdep1[e];
        sm[XW_WD2 + i*260 + j*16 + k] = wdep2[e];
    }
    sm[XW_BC  + tid] = bconv[tid];
    sm[XW_BD1 + tid] = bdep1[tid];
    sm[XW_BD2 + tid] = bdep2[tid];
    __syncthreads();

    const int wave = tid >> 6, lane = tid & 63;
    const int g = lane >> 4, s = lane & 15;
    const int pt0 = (blockIdx.x * 4 + wave) * 16;

    const int p = pt0 + s;
    const float r0 = rep[p*3], r1 = rep[p*3+1], r2 = rep[p*3+2];
    short8v ah0, al0, ah1, al1;
    #pragma unroll
    for (int e = 0; e < 8; ++e) {
        const int r = g*8 + e;
        const int d = g >> 1, k = r & 15;
        const float v = pts[p*48 + k*3 + d] - (d == 0 ? r0 : r1);
        const short h = f2bf(v);
        ah0[e] = h; al0[e] = f2bf(v - bf2f(h));
    }
    #pragma unroll
    for (int e = 0; e < 4; ++e) {
        const int k = g*4 + e;
        const float v = pts[p*48 + k*3 + 2] - r2;
        const short h = f2bf(v);
        ah1[e] = h; al1[e] = f2bf(v - bf2f(h));
    }
    #pragma unroll
    for (int e = 4; e < 8; ++e) { ah1[e] = 0; al1[e] = 0; }

    f32x4 ex[16];
    #pragma unroll
    for (int u = 0; u < 16; ++u) {
        const float b = sm[XW_BC + u*16 + s];
        f32x4 acc; acc[0] = b; acc[1] = b; acc[2] = b; acc[3] = b;
        const short8v bh0 = *(const short8v*)&smh[(u*64 + lane) * 8];
        const short8v bh1 = *(const short8v*)&smh[((16 + u)*64 + lane) * 8];
        acc = MFMA32(ah0, bh0, acc);
        acc = MFMA32(ah1, bh1, acc);
        acc = MFMA32(al0, bh0, acc);
        acc = MFMA32(al1, bh1, acc);
        f32x4 r;
        r[0] = ELU(acc[0]); r[1] = ELU(acc[1]); r[2] = ELU(acc[2]); r[3] = ELU(acc[3]);
        ex[u] = r;
    }

    const int scrb = XW_SCR + wave * 4368;
    #pragma unroll
    for (int j = 0; j < 16; ++j) {
        const float b = sm[XW_BD1 + s*16 + j];
        f32x4 a; a[0] = b; a[1] = b; a[2] = b; a[3] = b;
        #pragma unroll
        for (int kb = 0; kb < 4; ++kb) {
            const float4 w = *(const float4*)&sm[XW_WD1 + s*260 + j*16 + kb*4];
            a += ex[kb*4+0] * w.x; a += ex[kb*4+1] * w.y;
            a += ex[kb*4+2] * w.z; a += ex[kb*4+3] * w.w;
        }
        #pragma unroll
        for (int q = 0; q < 4; ++q)
            sm[scrb + (g*4+q)*273 + j*17 + s] = ELU(a[q]);
    }
    lds_fence();

    f32x4 xr[16];
    #pragma unroll
    for (int k = 0; k < 16; ++k) {
        f32x4 v;
        #pragma unroll
        for (int q = 0; q < 4; ++q)
            v[q] = sm[scrb + (g*4+q)*273 + s*17 + k];
        xr[k] = v;
    }
    f32x4 oj[16];
    #pragma unroll
    for (int j = 0; j < 16; ++j) {
        const float b = sm[XW_BD2 + s*16 + j];
        f32x4 a; a[0] = b; a[1] = b; a[2] = b; a[3] = b;
        #pragma unroll
        for (int kb = 0; kb < 4; ++kb) {
            const float4 w = *(const float4*)&sm[XW_WD2 + s*260 + j*16 + kb*4];
            a += xr[kb*4+0] * w.x; a += xr[kb*4+1] * w.y;
            a += xr[kb*4+2] * w.z; a += xr[kb*4+3] * w.w;
        }
        oj[j] = a;
    }
    #pragma unroll
    for (int q = 0; q < 4; ++q) {
        const int pp = pt0 + g*4 + q;
        #pragma unroll
        for (int jb = 0; jb < 4; ++jb) {
            uint2 pk;
            pk.x = packbf(oj[jb*4+0][q], oj[jb*4+1][q]);
            pk.y = packbf(oj[jb*4+2][q], oj[jb*4+3][q]);
            *(uint2*)&x2bf[(size_t)pp*256 + s*16 + jb*4] = pk;
        }
    }
}

// ---------------- Kernel 2: MFMA features; swizzled DMA; counted vmcnt; pipelined B ----
// sfts swizzle sigma(W)=W^(8g) (g=W>>8&3): DMA source lane permuted (lane^2i, within-128B,
// coalescing-preserving), read index ^(8g) -> 2-way banks (free). vmcnt(11): stores count in
// vmcnt; 11 = stores(8)+freshDMA(4)-1 retires exactly DMA(pt)+scalars(pt), never drains stores.
#define NPTS 32768
#define TOTW 3072
__global__ __launch_bounds__(256, 3) void k_feat(
    const float* __restrict__ rep, const float* __restrict__ pts, const float* __restrict__ fts,
    const float* __restrict__ w1, const float* __restrict__ b1,
    const float* __restrict__ w2, const float* __restrict__ b2,
    const float* __restrict__ wdw, const float* __restrict__ bdw,
    const unsigned short* __restrict__ x2bf, unsigned short* __restrict__ tmpbf)
{
    __shared__ __align__(16) short sw2[4096];      // B-frags: rec r=nt*2+h, 16B @ (r*64+lane)
    __shared__ __align__(16) uint2 sw1[64];        // j: {pack(w1[0][j],w1[1][j]), pack(w1[2][j],b1[j])}
    __shared__ float sbdw[256];
    __shared__ __align__(16) float sfts[4][2][1024]; // [wave][buf][fts tile, sigma-swizzled]
    const int tid = threadIdx.x;

    for (int idx = tid; idx < 512; idx += 256) {   // 512 recs of 8 bf16
        const int r = idx >> 6, l = idx & 63;
        const int nt = r >> 1, h = r & 1, gg = l >> 4, ss = l & 15;
        short8v v;
        #pragma unroll
        for (int e = 0; e < 8; ++e)
            v[e] = f2bf(w2[(h*32 + gg*8 + e)*64 + nt*16 + ss]);
        *(short8v*)&sw2[idx * 8] = v;
    }
    if (tid < 64) {
        const int j = tid;
        uint2 v;
        v.x = packbf(w1[j], w1[64 + j]);
        v.y = packbf(w1[128 + j], b1[j]);
        sw1[j] = v;
    }
    sbdw[tid] = bdw[tid];
    __syncthreads();

    const int lane = tid & 63, wave = tid >> 6;
    const int g = lane >> 4, s = lane & 15;
    const int g8 = g * 8;

    float b2c[4];
    #pragma unroll
    for (int nt = 0; nt < 4; ++nt) b2c[nt] = b2[nt*16 + s];

    // ---- wdw -> per-lane regs (bf16 pairs), loop-invariant ----
    uint2 wp0[8], wp1[8];
    #pragma unroll
    for (int u = 0; u < 8; ++u) {
        const int cb = (u*16 + s) * 32 + 4*g;
        wp0[u].x = packbf(wdw[cb + 0],  wdw[cb + 1]);
        wp0[u].y = packbf(wdw[cb + 2],  wdw[cb + 3]);
        wp1[u].x = packbf(wdw[cb + 16], wdw[cb + 17]);
        wp1[u].y = packbf(wdw[cb + 18], wdw[cb + 19]);
    }

    const int gw = blockIdx.x * 4 + wave;   // 0..3071
    float* sf0 = &sfts[wave][0][0];
    float* sf1 = &sfts[wave][1][0];

    // ---- prologue: swizzled DMA pt=gw into buf0; prefetch scalars(gw) ----
    {
        const float* base = fts + (size_t)gw * 1024;
        #pragma unroll
        for (int i = 0; i < 4; ++i)
            gload_lds16(base + i*256 + (lane ^ (2*i))*4, sf0 + i*256);
    }
    ushort4 xv_n = *(const ushort4*)&x2bf[(size_t)gw*256 + s*16 + g*4];
    float p0_n = pts[gw*48 + s*3 + 0] - rep[gw*3 + 0];
    float p1_n = pts[gw*48 + s*3 + 1] - rep[gw*3 + 1];
    float p2_n = pts[gw*48 + s*3 + 2] - rep[gw*3 + 2];

    int k = 0;
    for (int pt = gw; pt < NPTS; pt += TOTW, ++k) {
        float* sfc = (k & 1) ? sf1 : sf0;
        float* sfn = (k & 1) ? sf0 : sf1;
        const int ptn = pt + TOTW;

        // ---- step 1: issue swizzled DMA(ptn) ----
        if (ptn < NPTS) {
            const float* base = fts + (size_t)ptn * 1024;
            #pragma unroll
            for (int i = 0; i < 4; ++i)
                gload_lds16(base + i*256 + (lane ^ (2*i))*4, sfn + i*256);
        }
        // ---- step 2: counted wait — retires DMA(pt)+scalars(pt), not stores/fresh ----
        asm volatile("s_waitcnt vmcnt(11)" ::: "memory");

        const ushort4 xv = xv_n;
        const float p0 = p0_n, p1 = p1_n, p2 = p2_n;

        // ---- step 3: scalar prefetch(ptn) ----
        if (ptn < NPTS) {
            xv_n = *(const ushort4*)&x2bf[(size_t)ptn*256 + s*16 + g*4];
            p0_n = pts[ptn*48 + s*3 + 0] - rep[ptn*3 + 0];
            p1_n = pts[ptn*48 + s*3 + 1] - rep[ptn*3 + 1];
            p2_n = pts[ptn*48 + s*3 + 2] - rep[ptn*3 + 2];
        }

        // ---- phase A: h1 in A-frag layout; h2 via 8 MFMA ----
        short8v af0, af1;
        #pragma unroll
        for (int t = 0; t < 2; ++t) {
            short8v f;
            #pragma unroll
            for (int e = 0; e < 8; ++e) {
                const uint2 pk = sw1[t*32 + g*8 + e];
                const float wx = __uint_as_float(pk.x << 16);
                const float wy = __uint_as_float(pk.x & 0xffff0000u);
                const float wz = __uint_as_float(pk.y << 16);
                const float bb = __uint_as_float(pk.y & 0xffff0000u);
                float h = bb + p0*wx + p1*wy + p2*wz;
                h = ELU(h);
                f[e] = f2bf(h);
            }
            if (t == 0) af0 = f; else af1 = f;
        }
        f32x4 hacc[4];
        #pragma unroll
        for (int nt = 0; nt < 4; ++nt) {
            f32x4 a; a[0] = b2c[nt]; a[1] = b2c[nt]; a[2] = b2c[nt]; a[3] = b2c[nt];
            const short8v bf0 = *(const short8v*)&sw2[((nt*2 + 0)*64 + lane) * 8];
            const short8v bf1 = *(const short8v*)&sw2[((nt*2 + 1)*64 + lane) * 8];
            a = MFMA32(af0, bf0, a);
            a = MFMA32(af1, bf1, a);
            hacc[nt] = a;
        }
        short8v a2 = (short8v)0;
        a2[0] = (short)xv.x; a2[1] = (short)xv.y;
        a2[2] = (short)xv.z; a2[3] = (short)xv.w;

        // ---- phase B: software-pipelined (bfrag/MFMA one tile ahead of dot) ----
        f32x4 z; z[0] = 0.f; z[1] = 0.f; z[2] = 0.f; z[3] = 0.f;
        float q0a[8], q1a[8];
        short8v bf_c = (short8v)0;
        #pragma unroll
        for (int q = 0; q < 4; ++q) bf_c[q] = f2bf(ELU(hacc[0][q]));
        f32x4 fx_c = MFMA32(a2, bf_c, z);
        #pragma unroll
        for (int u = 0; u < 8; ++u) {
            f32x4 fx_n;
            if (u < 7) {
                const int un = u + 1;
                short8v bf_n = (short8v)0;
                if (un < 4) {
                    #pragma unroll
                    for (int q = 0; q < 4; ++q) bf_n[q] = f2bf(ELU(hacc[un][q]));
                } else {
                    #pragma unroll
                    for (int e = 0; e < 4; ++e)
                        bf_n[e] = f2bf(sfc[(g*4 + e)*64 + (((un - 4)*16 + s) ^ g8)]);
                }
                fx_n = MFMA32(a2, bf_n, z);
            }
            const float a0 = __uint_as_float(wp0[u].x << 16);
            const float a1 = __uint_as_float(wp0[u].x & 0xffff0000u);
            const float a2f = __uint_as_float(wp0[u].y << 16);
            const float a3 = __uint_as_float(wp0[u].y & 0xffff0000u);
            const float c0 = __uint_as_float(wp1[u].x << 16);
            const float c1 = __uint_as_float(wp1[u].x & 0xffff0000u);
            const float c2 = __uint_as_float(wp1[u].y << 16);
            const float c3 = __uint_as_float(wp1[u].y & 0xffff0000u);
            q0a[u] = fx_c[0]*a0 + fx_c[1]*a1 + fx_c[2]*a2f + fx_c[3]*a3;
            q1a[u] = fx_c[0]*c0 + fx_c[1]*c1 + fx_c[2]*c2 + fx_c[3]*c3;
            if (u < 7) fx_c = fx_n;
        }
        // ---- batched xor-16 ----
        #pragma unroll
        for (int u = 0; u < 8; ++u) {
            q0a[u] += __shfl_xor(q0a[u], 16);
            q1a[u] += __shfl_xor(q1a[u], 16);
        }
        // ---- xor-32 via permlane32_swap ----
        #pragma unroll
        for (int u = 0; u < 8; ++u) {
            q0a[u] = xor32_add(q0a[u]);
            q1a[u] = xor32_add(q1a[u]);
        }
        if (lane < 16) {   // g==0, s=lane
            #pragma unroll
            for (int u = 0; u < 8; ++u) {
                const int c = u*16 + s;
                const unsigned pk = packbf(q0a[u] + sbdw[2*c], q1a[u] + sbdw[2*c + 1]);
                *(unsigned*)&tmpbf[(size_t)pt*256 + 2*c] = pk;
            }
        }
    }
}

// ---------------- Kernel 3: out = elu(tmp_bf16 @ wpw^T + bpw) via MFMA ----------------
__global__ __launch_bounds__(256) void k_out(
    const unsigned short* __restrict__ tmp, const float* __restrict__ wpw,
    const float* __restrict__ bpw, float* __restrict__ out)
{
    __shared__ unsigned sb[16384];   // 64KB: [n][chunk cb^(n&7)][wi]
    const int tid = threadIdx.x;
    for (int e = tid; e < 16384; e += 256) {
        const int n = e >> 7, kw = e & 127;
        const int cb = kw >> 2, wi = kw & 3;
        const unsigned lo = (unsigned)(unsigned short)f2bf(wpw[n*256 + 2*kw]);
        const unsigned hi = (unsigned)(unsigned short)f2bf(wpw[n*256 + 2*kw + 1]);
        sb[n*128 + ((cb ^ (n & 7)) << 2) + wi] = lo | (hi << 16);
    }
    __syncthreads();

    const int lane = tid & 63, wave = tid >> 6;
    const int g = lane >> 4, s = lane & 15;
    const int row = blockIdx.x * 64 + wave * 16 + s;

    f32x4 acc[8];
    #pragma unroll
    for (int nt = 0; nt < 8; ++nt) {
        const float b = bpw[nt*16 + s];
        acc[nt][0] = b; acc[nt][1] = b; acc[nt][2] = b; acc[nt][3] = b;
    }

    const unsigned short* arow = tmp + (size_t)row * 256 + g*8;
    short8v pa = *(const short8v*)(arow);

    #pragma unroll
    for (int kk = 0; kk < 8; ++kk) {
        const short8v a = pa;
        if (kk < 7) pa = *(const short8v*)(arow + (kk+1)*32);
        #pragma unroll
        for (int nt = 0; nt < 8; ++nt) {
            const short8v bf = *(const short8v*)&sb[(nt*16 + s)*128 + (((kk*4 + g) ^ (s & 7)) << 2)];
            acc[nt] = MFMA32(a, bf, acc[nt]);
        }
    }
    const int rbase = blockIdx.x * 64 + wave * 16 + 4*g;
    #pragma unroll
    for (int nt = 0; nt < 8; ++nt)
        #pragma unroll
        for (int q = 0; q < 4; ++q)
            out[(size_t)(rbase + q) * 128 + nt*16 + s] = ELU(acc[nt][q]);
}

extern "C" void kernel_launch(void* const* d_in, const int* in_sizes, int n_in,
                              void* d_out, int out_size, void* d_ws, size_t ws_size,
                              hipStream_t stream)
{
    (void)in_sizes; (void)n_in; (void)out_size; (void)ws_size;
    const float* rep   = (const float*)d_in[0];
    const float* pts   = (const float*)d_in[1];
    const float* fts   = (const float*)d_in[2];
    const float* w1    = (const float*)d_in[3];
    const float* b1    = (const float*)d_in[4];
    const float* w2    = (const float*)d_in[5];
    const float* b2    = (const float*)d_in[6];
    const float* wconv = (const float*)d_in[7];
    const float* bconv = (const float*)d_in[8];
    const float* wdep1 = (const float*)d_in[9];
    const float* bdep1 = (const float*)d_in[10];
    const float* wdep2 = (const float*)d_in[11];
    const float* bdep2 = (const float*)d_in[12];
    const float* wdw   = (const float*)d_in[13];
    const float* bdw   = (const float*)d_in[14];
    const float* wpw   = (const float*)d_in[15];
    const float* bpw   = (const float*)d_in[16];
    float* out  = (float*)d_out;
    unsigned short* x2bf  = (unsigned short*)d_ws;                       // 16.8 MB
    unsigned short* tmpbf = (unsigned short*)((char*)d_ws + (size_t)32 * 1024 * 1024); // 16.8 MB

    hipFuncSetAttribute((const void*)k_xform, hipFuncAttributeMaxDynamicSharedMemorySize, XW_TOTAL*4);

    k_xform<<<dim3(512), dim3(256), XW_TOTAL*4, stream>>>(rep, pts, wconv, bconv, wdep1, bdep1, wdep2, bdep2, x2bf);
    k_feat <<<dim3(768), dim3(256), 0, stream>>>(rep, pts, fts, w1, b1, w2, b2, wdw, bdw, x2bf, tmpbf);
    k_out  <<<dim3(512), dim3(256), 0, stream>>>(tmpbf, wpw, bpw, out);
}